// Round 1
// baseline (7099.872 us; speedup 1.0000x reference)
//
#include <hip/hip_runtime.h>
#include <stdint.h>

#define B 16
#define CIN 32
#define C 64
#define H 256
#define W 256
#define OH 86
#define OW 86
#define PIX (OH*OW)   // 7396
#define NT 29         // ceil(7396/256) tiles per (n,co)

// ---- workspace layout (bytes) ----
#define OFF_D      0                         // 3 floats: d11,d1,d2
#define OFF_MAP1   64                        // 96 int8: map for conv1 input (32ch x {-1,0,1})
#define OFF_S1     256                       // 64 f32 bn1 scale
#define OFF_SH1    512                       // 64 f32 bn1 shift
#define OFF_B11    768                       // 64 int32 ternary bias
#define OFF_B1     1024                      // 64 int32
#define OFF_B2     1280                      // 64 int32
#define OFF_W11I   4096                      // 64*288 int32 = 73728
#define OFF_W1B    77824                     // 18432 int8
#define OFF_W2I    96256                     // 64*576 int32 = 147456
#define OFF_XT     262144                    // 33554432 int8 (x ternarized)
#define OFF_PREV   33816576                  // 7573504 int16 (shortcut conv out)
#define OFF_T2     48963584                  // 67108864 int8 (conv2 input, ternary)
// total ws need: ~116 MB

// ---------------- K0: d = 0.1 * max|w| ----------------
__global__ __launch_bounds__(256) void k_absmax(const float* w11, const float* w1,
                                                const float* w2, float* dws) {
    __shared__ float red[256];
    int b = blockIdx.x;
    const float* p = (b == 0) ? w11 : (b == 1) ? w1 : w2;
    int n = (b == 2) ? 36864 : 18432;
    float m = 0.f;
    for (int i = threadIdx.x; i < n; i += 256) m = fmaxf(m, fabsf(p[i]));
    red[threadIdx.x] = m; __syncthreads();
    for (int s = 128; s > 0; s >>= 1) {
        if (threadIdx.x < s) red[threadIdx.x] = fmaxf(red[threadIdx.x], red[threadIdx.x + s]);
        __syncthreads();
    }
    if (threadIdx.x == 0) dws[b] = __fmul_rn(0.1f, red[0]);
}

// ---------------- K1: ternarize weights/biases, build tables ----------------
__global__ __launch_bounds__(256) void k_prep(const float* w11, const float* w1, const float* w2,
                                              const float* b11, const float* b1, const float* b2,
                                              const float* gp, const float* bp, const float* mp, const float* vp,
                                              const float* g1, const float* be1, const float* me1, const float* v1,
                                              char* ws) {
    const float* dws = (const float*)(ws + OFF_D);
    float d11 = dws[0], d1 = dws[1], d2v = dws[2];
    int idx = blockIdx.x * 256 + threadIdx.x;
    if (idx < 18432) {
        float t = w11[idx];
        ((int*)(ws + OFF_W11I))[idx] = (fabsf(t) < d11) ? 0 : (t > 0.f ? 1 : -1);
    } else if (idx < 36864) {
        int i = idx - 18432;
        float t = w1[i];
        ((signed char*)(ws + OFF_W1B))[i] = (fabsf(t) < d1) ? 0 : (t > 0.f ? 1 : -1);
    } else if (idx < 73728) {
        int i = idx - 36864;
        float t = w2[i];
        ((int*)(ws + OFF_W2I))[i] = (fabsf(t) < d2v) ? 0 : (t > 0.f ? 1 : -1);
    } else {
        int i = idx - 73728;
        if (i < 64) {
            float t = b11[i];
            ((int*)(ws + OFF_B11))[i] = (fabsf(t) < d11) ? 0 : (t > 0.f ? 1 : -1);
        } else if (i < 128) {
            float t = b1[i - 64];
            ((int*)(ws + OFF_B1))[i - 64] = (fabsf(t) < d1) ? 0 : (t > 0.f ? 1 : -1);
        } else if (i < 192) {
            float t = b2[i - 128];
            ((int*)(ws + OFF_B2))[i - 128] = (fabsf(t) < d2v) ? 0 : (t > 0.f ? 1 : -1);
        } else if (i < 288) {
            // map1[c][v+1] = tern(lrelu(bn_pre(v)), d1), v in {-1,0,1}
            int j = i - 192;
            int c = j / 3, v = (j % 3) - 1;
            float inv = __fdiv_rn(gp[c], __fsqrt_rn(__fadd_rn(vp[c], 1e-5f)));
            float sh  = __fsub_rn(bp[c], __fmul_rn(mp[c], inv));
            float z   = __fadd_rn(__fmul_rn((float)v, inv), sh);
            z = (z > 0.f) ? z : __fmul_rn(0.01f, z);
            ((signed char*)(ws + OFF_MAP1))[j] = (fabsf(z) < d1) ? 0 : (z > 0.f ? 1 : -1);
        } else if (i < 352) {
            int c = i - 288;
            float inv = __fdiv_rn(g1[c], __fsqrt_rn(__fadd_rn(v1[c], 1e-5f)));
            ((float*)(ws + OFF_S1))[c]  = inv;
            ((float*)(ws + OFF_SH1))[c] = __fsub_rn(be1[c], __fmul_rn(me1[c], inv));
        }
    }
}

// ---------------- K2: x_t = tern(x, d11) as int8 ----------------
__global__ __launch_bounds__(256) void k_tern_x(const float4* __restrict__ x,
                                                char4* __restrict__ xt, const char* ws) {
    float d11 = ((const float*)(ws + OFF_D))[0];
    int i = blockIdx.x * 256 + threadIdx.x;  // 8388608 threads, 4 elems each
    float4 v = x[i];
    char4 r;
    r.x = (fabsf(v.x) < d11) ? 0 : (v.x > 0.f ? 1 : -1);
    r.y = (fabsf(v.y) < d11) ? 0 : (v.y > 0.f ? 1 : -1);
    r.z = (fabsf(v.z) < d11) ? 0 : (v.z > 0.f ? 1 : -1);
    r.w = (fabsf(v.w) < d11) ? 0 : (v.w > 0.f ? 1 : -1);
    xt[i] = r;
}

// ---------------- K3: shortcut conv11, stride 3, int16 out ----------------
__global__ __launch_bounds__(256) void k_conv11(const char* __restrict__ ws) {
    int bid = blockIdx.x;
    int co = bid & 63;
    int t  = bid >> 6;
    int tile = t % NT;
    int n = t / NT;
    int pix = tile * 256 + threadIdx.x;
    if (pix >= PIX) return;
    int oh = pix / OW, ow = pix % OW;
    const signed char* xt = (const signed char*)(ws + OFF_XT) + n * CIN * H * W;
    const int* wv = (const int*)(ws + OFF_W11I) + co * 288;
    int acc = 0;
    for (int ci = 0; ci < CIN; ci++) {
        const signed char* xp = xt + ci * H * W;
        #pragma unroll
        for (int kh = 0; kh < 3; kh++) {
            int ih = oh * 3 - 1 + kh;
            if ((unsigned)ih >= H) continue;
            #pragma unroll
            for (int kw = 0; kw < 3; kw++) {
                int iw = ow * 3 - 1 + kw;
                if ((unsigned)iw >= W) continue;
                acc += wv[ci * 9 + kh * 3 + kw] * (int)xp[ih * W + iw];
            }
        }
    }
    acc += ((const int*)(ws + OFF_B11))[co];
    ((short*)(ws + OFF_PREV))[(n * C + co) * PIX + pix] = (short)acc;
}

// ---------------- K4: conv1 stride 1 fused (the hot kernel) ----------------
// block = (n, 16x16 spatial tile); all 64 co accumulated in registers.
__global__ __launch_bounds__(256) void k_conv1(const char* __restrict__ ws) {
    __shared__ signed char wl[C * 288];        // 18432
    __shared__ signed char tin[CIN * 18 * 18]; // 10368
    __shared__ signed char mapl[96];

    int bid = blockIdx.x;
    int tw = bid & 15, th = (bid >> 4) & 15, n = bid >> 8;
    int tid = threadIdx.x;

    if (tid < 96) mapl[tid] = ((const signed char*)(ws + OFF_MAP1))[tid];
    __syncthreads();

    for (int i = tid; i < C * 288; i += 256)
        wl[i] = ((const signed char*)(ws + OFF_W1B))[i];

    const signed char* xtn = (const signed char*)(ws + OFF_XT) + n * CIN * H * W;
    int y0 = th * 16 - 1, x0 = tw * 16 - 1;
    for (int i = tid; i < CIN * 18 * 18; i += 256) {
        int ci = i / 324;
        int r = i % 324;
        int dy = r / 18, dx = r % 18;
        int gy = y0 + dy, gx = x0 + dx;
        signed char v = 0;
        if ((unsigned)gy < H && (unsigned)gx < W) {
            int xv = xtn[ci * H * W + gy * W + gx];
            v = mapl[ci * 3 + xv + 1];
        }
        tin[i] = v;
    }
    __syncthreads();

    int tx = tid & 15, ty = tid >> 4;
    int acc[C];
    #pragma unroll
    for (int co = 0; co < C; co++) acc[co] = 0;

    #pragma unroll 1
    for (int ci = 0; ci < CIN; ci++) {
        #pragma unroll
        for (int kh = 0; kh < 3; kh++) {
            #pragma unroll
            for (int kw = 0; kw < 3; kw++) {
                int v = tin[ci * 324 + (ty + kh) * 18 + (tx + kw)];
                int kk = ci * 9 + kh * 3 + kw;
                #pragma unroll
                for (int co = 0; co < C; co++)
                    acc[co] += v * (int)wl[co * 288 + kk];
            }
        }
    }

    // fused: +b1, bn1, lrelu, tern(d2) -> int8 conv2 input
    const int* b1i = (const int*)(ws + OFF_B1);
    const float* s1 = (const float*)(ws + OFF_S1);
    const float* sh1 = (const float*)(ws + OFF_SH1);
    float d2v = ((const float*)(ws + OFF_D))[2];
    int h = th * 16 + ty, w = tw * 16 + tx;
    signed char* t2 = (signed char*)(ws + OFF_T2) + n * C * H * W;
    #pragma unroll
    for (int co = 0; co < C; co++) {
        int vi = acc[co] + b1i[co];
        float z = __fadd_rn(__fmul_rn((float)vi, s1[co]), sh1[co]);
        z = (z > 0.f) ? z : __fmul_rn(0.01f, z);
        signed char tv = (fabsf(z) < d2v) ? 0 : (z > 0.f ? 1 : -1);
        t2[co * H * W + h * W + w] = tv;
    }
}

// ---------------- K5: conv2 stride 3 fused + residual + lrelu ----------------
__global__ __launch_bounds__(256) void k_conv2(const char* __restrict__ ws,
                                               float* __restrict__ out) {
    int bid = blockIdx.x;
    int co = bid & 63;
    int t  = bid >> 6;
    int tile = t % NT;
    int n = t / NT;
    int pix = tile * 256 + threadIdx.x;
    if (pix >= PIX) return;
    int oh = pix / OW, ow = pix % OW;
    const signed char* t2 = (const signed char*)(ws + OFF_T2) + n * C * H * W;
    const int* wv = (const int*)(ws + OFF_W2I) + co * 576;
    int acc = 0;
    for (int ci = 0; ci < C; ci++) {
        const signed char* tp = t2 + ci * H * W;
        #pragma unroll
        for (int kh = 0; kh < 3; kh++) {
            int ih = oh * 3 - 1 + kh;
            if ((unsigned)ih >= H) continue;
            #pragma unroll
            for (int kw = 0; kw < 3; kw++) {
                int iw = ow * 3 - 1 + kw;
                if ((unsigned)iw >= W) continue;
                acc += wv[ci * 9 + kh * 3 + kw] * (int)tp[ih * W + iw];
            }
        }
    }
    acc += ((const int*)(ws + OFF_B2))[co];
    acc += (int)((const short*)(ws + OFF_PREV))[(n * C + co) * PIX + pix];
    float z = (float)acc;
    out[(n * C + co) * PIX + pix] = (z > 0.f) ? z : __fmul_rn(0.01f, z);
}

extern "C" void kernel_launch(void* const* d_in, const int* in_sizes, int n_in,
                              void* d_out, int out_size, void* d_ws, size_t ws_size,
                              hipStream_t stream) {
    const float* x    = (const float*)d_in[0];
    const float* w11  = (const float*)d_in[1];
    const float* b11  = (const float*)d_in[2];
    const float* w1   = (const float*)d_in[3];
    const float* b1   = (const float*)d_in[4];
    const float* w2   = (const float*)d_in[5];
    const float* b2   = (const float*)d_in[6];
    const float* gp   = (const float*)d_in[7];
    const float* bp   = (const float*)d_in[8];
    const float* mp   = (const float*)d_in[9];
    const float* vp   = (const float*)d_in[10];
    const float* g1   = (const float*)d_in[11];
    const float* be1  = (const float*)d_in[12];
    const float* me1  = (const float*)d_in[13];
    const float* v1   = (const float*)d_in[14];
    char* ws = (char*)d_ws;
    float* out = (float*)d_out;

    k_absmax<<<3, 256, 0, stream>>>(w11, w1, w2, (float*)(ws + OFF_D));
    k_prep<<<290, 256, 0, stream>>>(w11, w1, w2, b11, b1, b2,
                                    gp, bp, mp, vp, g1, be1, me1, v1, ws);
    k_tern_x<<<32768, 256, 0, stream>>>((const float4*)x, (char4*)(ws + OFF_XT), ws);
    k_conv11<<<64 * NT * B, 256, 0, stream>>>(ws);
    k_conv1<<<4096, 256, 0, stream>>>(ws);
    k_conv2<<<64 * NT * B, 256, 0, stream>>>(ws, out);
}

// Round 3
// 433.212 us; speedup vs baseline: 16.3889x; 16.3889x over previous
//
#include <hip/hip_runtime.h>
#include <stdint.h>

#define B 16
#define CIN 32
#define C 64
#define H 256
#define W 256
#define OH 86
#define OW 86
#define PIX (OH*OW)   // 7396

// ---- workspace layout (bytes) ----
#define OFF_D      0          // 3 f32: d11,d1,d2
#define OFF_MAP1   64         // 96 i8
#define OFF_S1     256        // 64 f32
#define OFF_SH1    512        // 64 f32
#define OFF_B11    768        // 64 i32
#define OFF_B1     1024       // 64 i32
#define OFF_B2     1280       // 64 i32
#define OFF_W11P   4096       // 4608 i32, [k=pos*8+g][co64]
#define OFF_W1P    24576      // 4608 i32, [k=pos*8+g][co64]
#define OFF_W2P    45056      // 9216 i32, [k=pos*16+g][co64]
#define OFF_XTP    262144     // 16n*8g*65536 i32 = 32MB, [n][g][y][x]
#define OFF_PREV   33816576   // i16 [n][co][pix]
#define OFF_T2P    48963584   // 16n*16g*65536 i32 = 64MB, [n][g][y][x]

__device__ __forceinline__ int dot4(int a, int b, int c) {
    return __builtin_amdgcn_sdot4(a, b, c, false);
}

__device__ __forceinline__ int tern_i(float t, float d) {
    return (fabsf(t) < d) ? 0 : (t > 0.f ? 1 : -1);
}

// ---------------- K0: d = 0.1 * max|w| ----------------
__global__ __launch_bounds__(256) void k_absmax(const float* w11, const float* w1,
                                                const float* w2, float* dws) {
    __shared__ float red[256];
    int b = blockIdx.x;
    const float* p = (b == 0) ? w11 : (b == 1) ? w1 : w2;
    int n = (b == 2) ? 36864 : 18432;
    float m = 0.f;
    for (int i = threadIdx.x; i < n; i += 256) m = fmaxf(m, fabsf(p[i]));
    red[threadIdx.x] = m; __syncthreads();
    for (int s = 128; s > 0; s >>= 1) {
        if (threadIdx.x < s) red[threadIdx.x] = fmaxf(red[threadIdx.x], red[threadIdx.x + s]);
        __syncthreads();
    }
    if (threadIdx.x == 0) dws[b] = __fmul_rn(0.1f, red[0]);
}

// ---------------- K1: pack weights k-major, tables ----------------
__global__ __launch_bounds__(256) void k_prep(const float* w11, const float* w1, const float* w2,
                                              const float* b11, const float* b1, const float* b2,
                                              const float* gp, const float* bp, const float* mp, const float* vp,
                                              const float* g1, const float* be1, const float* me1, const float* v1,
                                              char* ws) {
    const float* dws = (const float*)(ws + OFF_D);
    float d11 = dws[0], d1 = dws[1], d2v = dws[2];
    int idx = blockIdx.x * 256 + threadIdx.x;
    if (idx < 4608) {                       // w1p [k][co], k=pos*8+g, bytes ci=4g+j
        int k = idx >> 6, co = idx & 63;
        int pos = k >> 3, g = k & 7;
        unsigned wd = 0;
        #pragma unroll
        for (int j = 0; j < 4; j++) {
            int tv = tern_i(w1[(co * 32 + g * 4 + j) * 9 + pos], d1);
            wd |= ((unsigned)(tv & 255)) << (8 * j);
        }
        ((int*)(ws + OFF_W1P))[idx] = (int)wd;
    } else if (idx < 9216) {                // w11p
        int i2 = idx - 4608;
        int k = i2 >> 6, co = i2 & 63;
        int pos = k >> 3, g = k & 7;
        unsigned wd = 0;
        #pragma unroll
        for (int j = 0; j < 4; j++) {
            int tv = tern_i(w11[(co * 32 + g * 4 + j) * 9 + pos], d11);
            wd |= ((unsigned)(tv & 255)) << (8 * j);
        }
        ((int*)(ws + OFF_W11P))[i2] = (int)wd;
    } else if (idx < 18432) {               // w2p [k][co], k=pos*16+g
        int i2 = idx - 9216;
        int k = i2 >> 6, co = i2 & 63;
        int pos = k >> 4, g = k & 15;
        unsigned wd = 0;
        #pragma unroll
        for (int j = 0; j < 4; j++) {
            int tv = tern_i(w2[(co * 64 + g * 4 + j) * 9 + pos], d2v);
            wd |= ((unsigned)(tv & 255)) << (8 * j);
        }
        ((int*)(ws + OFF_W2P))[i2] = (int)wd;
    } else {
        int i = idx - 18432;
        if (i < 64) {
            ((int*)(ws + OFF_B11))[i] = tern_i(b11[i], d11);
        } else if (i < 128) {
            ((int*)(ws + OFF_B1))[i - 64] = tern_i(b1[i - 64], d1);
        } else if (i < 192) {
            ((int*)(ws + OFF_B2))[i - 128] = tern_i(b2[i - 128], d2v);
        } else if (i < 288) {
            int j = i - 192;
            int c = j / 3, v = (j % 3) - 1;
            float inv = __fdiv_rn(gp[c], __fsqrt_rn(__fadd_rn(vp[c], 1e-5f)));
            float sh  = __fsub_rn(bp[c], __fmul_rn(mp[c], inv));
            float z   = __fadd_rn(__fmul_rn((float)v, inv), sh);
            z = (z > 0.f) ? z : __fmul_rn(0.01f, z);
            ((signed char*)(ws + OFF_MAP1))[j] = (signed char)tern_i(z, d1);
        } else if (i < 352) {
            int c = i - 288;
            float inv = __fdiv_rn(g1[c], __fsqrt_rn(__fadd_rn(v1[c], 1e-5f)));
            ((float*)(ws + OFF_S1))[c]  = inv;
            ((float*)(ws + OFF_SH1))[c] = __fsub_rn(be1[c], __fmul_rn(me1[c], inv));
        }
    }
}

// ---------------- K2: x -> packed ternary words [n][g][y][x] ----------------
__global__ __launch_bounds__(256) void k_tern_x(const float4* __restrict__ x,
                                                char* __restrict__ ws) {
    float d11 = ((const float*)(ws + OFF_D))[0];
    int idx = blockIdx.x * 256 + threadIdx.x;      // 2,097,152 threads
    int xq = idx & 63, y = (idx >> 6) & 255, g = (idx >> 14) & 7, n = idx >> 17;
    float4 f[4];
    #pragma unroll
    for (int k = 0; k < 4; k++)
        f[k] = x[((((n * 32 + g * 4 + k) << 16) + (y << 8)) >> 2) + xq];
    unsigned wd[4];
    #pragma unroll
    for (int j = 0; j < 4; j++) {
        float v0 = (j == 0) ? f[0].x : (j == 1) ? f[0].y : (j == 2) ? f[0].z : f[0].w;
        float v1 = (j == 0) ? f[1].x : (j == 1) ? f[1].y : (j == 2) ? f[1].z : f[1].w;
        float v2 = (j == 0) ? f[2].x : (j == 1) ? f[2].y : (j == 2) ? f[2].z : f[2].w;
        float v3 = (j == 0) ? f[3].x : (j == 1) ? f[3].y : (j == 2) ? f[3].z : f[3].w;
        wd[j] = ((unsigned)(tern_i(v0, d11) & 255))
              | ((unsigned)(tern_i(v1, d11) & 255) << 8)
              | ((unsigned)(tern_i(v2, d11) & 255) << 16)
              | ((unsigned)(tern_i(v3, d11) & 255) << 24);
    }
    int4* xtp = (int4*)(ws + OFF_XTP);
    xtp[((((n * 8 + g) << 16) + (y << 8)) >> 2) + xq] =
        make_int4((int)wd[0], (int)wd[1], (int)wd[2], (int)wd[3]);
}

// ---------------- K3: shortcut conv11, stride 3 -> prev (i16) ----------------
__global__ __launch_bounds__(256) void k_conv11(const char* __restrict__ ws) {
    __shared__ int wL[4608];        // [k=pos*8+g][co64]
    __shared__ int tinL[8 * 576];   // [g][24*24]
    int bid = blockIdx.x;
    int tx = bid % 11, ty = (bid / 11) % 11, n = bid / 121;
    int tid = threadIdx.x;
    for (int i = tid; i < 4608; i += 256) wL[i] = ((const int*)(ws + OFF_W11P))[i];
    const int* xtp = (const int*)(ws + OFF_XTP) + n * 8 * 65536;
    int y0 = ty * 24 - 1, x0 = tx * 24 - 1;
    for (int i = tid; i < 8 * 576; i += 256) {
        int g = i / 576, r = i % 576, dy = r / 24, dx = r % 24;
        int gy = y0 + dy, gx = x0 + dx;
        int v = 0;
        if ((unsigned)gy < H && (unsigned)gx < W) v = xtp[g * 65536 + gy * 256 + gx];
        tinL[i] = v;
    }
    __syncthreads();
    int p2 = tid >> 3, cg = tid & 7;
    int py = p2 >> 2, px0 = (p2 & 3) * 2;
    int acc[2][8] = {};
    #pragma unroll 1
    for (int pos = 0; pos < 9; ++pos) {
        int kh = pos / 3, kw = pos - kh * 3;
        int ib = (py * 3 + kh) * 24 + px0 * 3 + kw;
        #pragma unroll
        for (int g = 0; g < 8; ++g) {
            int a0 = tinL[g * 576 + ib];
            int a1 = tinL[g * 576 + ib + 3];
            const int4* wp = (const int4*)&wL[(pos * 8 + g) * 64 + cg * 8];
            int4 u0 = wp[0], u1 = wp[1];
            acc[0][0] = dot4(a0, u0.x, acc[0][0]); acc[1][0] = dot4(a1, u0.x, acc[1][0]);
            acc[0][1] = dot4(a0, u0.y, acc[0][1]); acc[1][1] = dot4(a1, u0.y, acc[1][1]);
            acc[0][2] = dot4(a0, u0.z, acc[0][2]); acc[1][2] = dot4(a1, u0.z, acc[1][2]);
            acc[0][3] = dot4(a0, u0.w, acc[0][3]); acc[1][3] = dot4(a1, u0.w, acc[1][3]);
            acc[0][4] = dot4(a0, u1.x, acc[0][4]); acc[1][4] = dot4(a1, u1.x, acc[1][4]);
            acc[0][5] = dot4(a0, u1.y, acc[0][5]); acc[1][5] = dot4(a1, u1.y, acc[1][5]);
            acc[0][6] = dot4(a0, u1.z, acc[0][6]); acc[1][6] = dot4(a1, u1.z, acc[1][6]);
            acc[0][7] = dot4(a0, u1.w, acc[0][7]); acc[1][7] = dot4(a1, u1.w, acc[1][7]);
        }
    }
    const int* b11i = (const int*)(ws + OFF_B11);
    short* prev = (short*)(ws + OFF_PREV) + n * C * PIX;
    int oh = ty * 8 + py;
    if (oh < OH) {
        #pragma unroll
        for (int j = 0; j < 2; ++j) {
            int ow = tx * 8 + px0 + j;
            if (ow < OW) {
                #pragma unroll
                for (int i = 0; i < 8; ++i) {
                    int co = cg * 8 + i;
                    prev[co * PIX + oh * OW + ow] = (short)(acc[j][i] + b11i[co]);
                }
            }
        }
    }
}

// ---------------- K4: conv1 stride 1 fused (hot) ----------------
__global__ __launch_bounds__(256) void k_conv1(const char* __restrict__ ws) {
    __shared__ int wl[4608];        // [k=pos*8+g][co64]
    __shared__ int tinp[8 * 324];   // [g][18*18] packed mapped ternary
    __shared__ signed char mapl[96];
    int bid = blockIdx.x;
    int twx = bid & 15, twy = (bid >> 4) & 15, n = bid >> 8;
    int tid = threadIdx.x;
    if (tid < 96) mapl[tid] = ((const signed char*)(ws + OFF_MAP1))[tid];
    for (int i = tid; i < 4608; i += 256) wl[i] = ((const int*)(ws + OFF_W1P))[i];
    __syncthreads();
    const int* xtp = (const int*)(ws + OFF_XTP) + n * 8 * 65536;
    int y0 = twy * 16 - 1, x0 = twx * 16 - 1;
    for (int i = tid; i < 2592; i += 256) {
        int g = i / 324, r = i % 324, dy = r / 18, dx = r % 18;
        int gy = y0 + dy, gx = x0 + dx;
        int v = 0;
        if ((unsigned)gy < H && (unsigned)gx < W) {
            int w = xtp[g * 65536 + gy * 256 + gx];
            int b0 = (signed char)(w & 255);
            int b1 = (signed char)((w >> 8) & 255);
            int b2 = (signed char)((w >> 16) & 255);
            int b3 = (signed char)((w >> 24) & 255);
            unsigned m0 = (unsigned)(mapl[(g * 4 + 0) * 3 + b0 + 1] & 255);
            unsigned m1 = (unsigned)(mapl[(g * 4 + 1) * 3 + b1 + 1] & 255);
            unsigned m2 = (unsigned)(mapl[(g * 4 + 2) * 3 + b2 + 1] & 255);
            unsigned m3 = (unsigned)(mapl[(g * 4 + 3) * 3 + b3 + 1] & 255);
            v = (int)(m0 | (m1 << 8) | (m2 << 16) | (m3 << 24));
        }
        tinp[i] = v;
    }
    __syncthreads();
    int cg = tid >> 6, t = tid & 63;
    int row = t >> 2, xb = (t & 3) * 4;
    int acc[16][4] = {};
    #pragma unroll 1
    for (int pos = 0; pos < 9; ++pos) {
        int kh = pos / 3, kw = pos - kh * 3;
        int ib = (row + kh) * 18 + xb + kw;
        #pragma unroll
        for (int g = 0; g < 8; ++g) {
            int a[4];
            #pragma unroll
            for (int j = 0; j < 4; ++j) a[j] = tinp[g * 324 + ib + j];
            const int4* wp = (const int4*)&wl[(pos * 8 + g) * 64 + cg * 16];
            int4 u0 = wp[0], u1 = wp[1], u2 = wp[2], u3 = wp[3];
            int wv[16] = {u0.x,u0.y,u0.z,u0.w, u1.x,u1.y,u1.z,u1.w,
                          u2.x,u2.y,u2.z,u2.w, u3.x,u3.y,u3.z,u3.w};
            #pragma unroll
            for (int c = 0; c < 16; ++c)
                #pragma unroll
                for (int j = 0; j < 4; ++j)
                    acc[c][j] = dot4(a[j], wv[c], acc[c][j]);
        }
    }
    // fused epilogue: +b1, bn1, lrelu, tern(d2) -> packed t2p words
    const int* b1i = (const int*)(ws + OFF_B1);
    const float* s1 = (const float*)(ws + OFF_S1);
    const float* sh1 = (const float*)(ws + OFF_SH1);
    float d2v = ((const float*)(ws + OFF_D))[2];
    int Y = twy * 16 + row, X = twx * 16 + xb;
    int* t2p = (int*)(ws + OFF_T2P) + n * 16 * 65536;
    #pragma unroll
    for (int q = 0; q < 4; ++q) {
        int wds[4];
        #pragma unroll
        for (int j = 0; j < 4; ++j) {
            unsigned wd = 0;
            #pragma unroll
            for (int bb = 0; bb < 4; ++bb) {
                int c = q * 4 + bb;
                int co = cg * 16 + c;
                int vi = acc[c][j] + b1i[co];
                float z = __fadd_rn(__fmul_rn((float)vi, s1[co]), sh1[co]);
                z = (z > 0.f) ? z : __fmul_rn(0.01f, z);
                int tv = (fabsf(z) < d2v) ? 0 : (z > 0.f ? 1 : -1);
                wd |= ((unsigned)(tv & 255)) << (8 * bb);
            }
            wds[j] = (int)wd;
        }
        int gw = cg * 4 + q;
        *(int4*)&t2p[gw * 65536 + Y * 256 + X] = make_int4(wds[0], wds[1], wds[2], wds[3]);
    }
}

// ---------------- K5: conv2 stride 3 fused + residual + lrelu ----------------
__global__ __launch_bounds__(256) void k_conv2(const char* __restrict__ ws,
                                               float* __restrict__ out) {
    __shared__ int wL[4608];         // [k=pos*16+g][co32 half]
    __shared__ int tinL[16 * 576];   // [g][24*24]
    int bid = blockIdx.x;
    int half = bid & 1;
    int t = bid >> 1;
    int tx = t % 11, ty = (t / 11) % 11, n = t / 121;
    int tid = threadIdx.x;
    const int* w2p = (const int*)(ws + OFF_W2P);
    for (int i = tid; i < 4608; i += 256) {
        int k = i >> 5, c = i & 31;
        wL[i] = w2p[k * 64 + half * 32 + c];
    }
    const int* t2p = (const int*)(ws + OFF_T2P) + n * 16 * 65536;
    int y0 = ty * 24 - 1, x0 = tx * 24 - 1;
    for (int i = tid; i < 16 * 576; i += 256) {
        int g = i / 576, r = i % 576, dy = r / 24, dx = r % 24;
        int gy = y0 + dy, gx = x0 + dx;
        int v = 0;
        if ((unsigned)gy < H && (unsigned)gx < W) v = t2p[g * 65536 + gy * 256 + gx];
        tinL[i] = v;
    }
    __syncthreads();
    int p2 = tid >> 3, cg = tid & 7;
    int py = p2 >> 2, px0 = (p2 & 3) * 2;
    int acc[2][4] = {};
    #pragma unroll 1
    for (int pos = 0; pos < 9; ++pos) {
        int kh = pos / 3, kw = pos - kh * 3;
        int ib = (py * 3 + kh) * 24 + px0 * 3 + kw;
        #pragma unroll
        for (int g = 0; g < 16; ++g) {
            int a0 = tinL[g * 576 + ib];
            int a1 = tinL[g * 576 + ib + 3];
            int4 u = *(const int4*)&wL[(pos * 16 + g) * 32 + cg * 4];
            acc[0][0] = dot4(a0, u.x, acc[0][0]); acc[1][0] = dot4(a1, u.x, acc[1][0]);
            acc[0][1] = dot4(a0, u.y, acc[0][1]); acc[1][1] = dot4(a1, u.y, acc[1][1]);
            acc[0][2] = dot4(a0, u.z, acc[0][2]); acc[1][2] = dot4(a1, u.z, acc[1][2]);
            acc[0][3] = dot4(a0, u.w, acc[0][3]); acc[1][3] = dot4(a1, u.w, acc[1][3]);
        }
    }
    const int* b2i = (const int*)(ws + OFF_B2);
    const short* prev = (const short*)(ws + OFF_PREV) + n * C * PIX;
    int oh = ty * 8 + py;
    if (oh < OH) {
        #pragma unroll
        for (int j = 0; j < 2; ++j) {
            int ow = tx * 8 + px0 + j;
            if (ow < OW) {
                #pragma unroll
                for (int i = 0; i < 4; ++i) {
                    int co = half * 32 + cg * 4 + i;
                    int a = acc[j][i] + b2i[co] + (int)prev[co * PIX + oh * OW + ow];
                    float z = (float)a;
                    out[(n * C + co) * PIX + oh * OW + ow] = (z > 0.f) ? z : __fmul_rn(0.01f, z);
                }
            }
        }
    }
}

extern "C" void kernel_launch(void* const* d_in, const int* in_sizes, int n_in,
                              void* d_out, int out_size, void* d_ws, size_t ws_size,
                              hipStream_t stream) {
    const float* x    = (const float*)d_in[0];
    const float* w11  = (const float*)d_in[1];
    const float* b11  = (const float*)d_in[2];
    const float* w1   = (const float*)d_in[3];
    const float* b1   = (const float*)d_in[4];
    const float* w2   = (const float*)d_in[5];
    const float* b2   = (const float*)d_in[6];
    const float* gp   = (const float*)d_in[7];
    const float* bp   = (const float*)d_in[8];
    const float* mp   = (const float*)d_in[9];
    const float* vp   = (const float*)d_in[10];
    const float* g1   = (const float*)d_in[11];
    const float* be1  = (const float*)d_in[12];
    const float* me1  = (const float*)d_in[13];
    const float* v1   = (const float*)d_in[14];
    char* ws = (char*)d_ws;
    float* out = (float*)d_out;

    k_absmax<<<3, 256, 0, stream>>>(w11, w1, w2, (float*)(ws + OFF_D));
    k_prep<<<74, 256, 0, stream>>>(w11, w1, w2, b11, b1, b2,
                                   gp, bp, mp, vp, g1, be1, me1, v1, ws);
    k_tern_x<<<8192, 256, 0, stream>>>((const float4*)x, ws);
    k_conv11<<<121 * B, 256, 0, stream>>>(ws);
    k_conv1<<<4096, 256, 0, stream>>>(ws);
    k_conv2<<<121 * B * 2, 256, 0, stream>>>(ws, out);
}

// Round 4
// 308.746 us; speedup vs baseline: 22.9958x; 1.4031x over previous
//
#include <hip/hip_runtime.h>
#include <stdint.h>

#define B 16
#define CIN 32
#define C 64
#define H 256
#define W 256
#define OH 86
#define OW 86
#define PIX (OH*OW)   // 7396

typedef int v4i __attribute__((ext_vector_type(4)));

// ---- workspace layout (bytes) ----
#define OFF_D      0          // 3 f32: d11,d1,d2
#define OFF_MAPW   64         // 24 i32: [g8][s3] packed mapped words (s = v+1)
#define OFF_S1     256        // 64 f32
#define OFF_SH1    512        // 64 f32
#define OFF_B11    768        // 64 i32
#define OFF_B1     1024       // 64 i32
#define OFF_B2     1280       // 64 i32
#define OFF_W11P   4096       // 4608 i32, [k=pos*8+g][co64]
#define OFF_W1P    24576      // 4608 i32, [k=pos*8+g][co64]
#define OFF_W2P    45056      // 9216 i32, [k=pos*16+g][co64]
#define OFF_XTP    262144     // [n16][y256][x256][g8] i32 = 32MB (raw tern(x))
#define OFF_PREV   33816576   // i16 [n][co][pix]
#define OFF_T2P    48963584   // [n16][gw16][y256][x256] i32 = 64MB

__device__ __forceinline__ int dot4(int a, int b, int c) {
    return __builtin_amdgcn_sdot4(a, b, c, false);
}

__device__ __forceinline__ int tern_i(float t, float d) {
    return (fabsf(t) < d) ? 0 : (t > 0.f ? 1 : -1);
}

// ---------------- K0: d = 0.1 * max|w| ----------------
__global__ __launch_bounds__(256) void k_absmax(const float* w11, const float* w1,
                                                const float* w2, float* dws) {
    __shared__ float red[256];
    int b = blockIdx.x;
    const float* p = (b == 0) ? w11 : (b == 1) ? w1 : w2;
    int n = (b == 2) ? 36864 : 18432;
    float m = 0.f;
    for (int i = threadIdx.x; i < n; i += 256) m = fmaxf(m, fabsf(p[i]));
    red[threadIdx.x] = m; __syncthreads();
    for (int s = 128; s > 0; s >>= 1) {
        if (threadIdx.x < s) red[threadIdx.x] = fmaxf(red[threadIdx.x], red[threadIdx.x + s]);
        __syncthreads();
    }
    if (threadIdx.x == 0) dws[b] = __fmul_rn(0.1f, red[0]);
}

// ---------------- K1: pack weights k-major, tables ----------------
__global__ __launch_bounds__(256) void k_prep(const float* w11, const float* w1, const float* w2,
                                              const float* b11, const float* b1, const float* b2,
                                              const float* gp, const float* bp, const float* mp, const float* vp,
                                              const float* g1, const float* be1, const float* me1, const float* v1,
                                              char* ws) {
    const float* dws = (const float*)(ws + OFF_D);
    float d11 = dws[0], d1 = dws[1], d2v = dws[2];
    int idx = blockIdx.x * 256 + threadIdx.x;
    if (idx < 4608) {                       // w1p [k][co], k=pos*8+g, bytes ci=4g+j
        int k = idx >> 6, co = idx & 63;
        int pos = k >> 3, g = k & 7;
        unsigned wd = 0;
        #pragma unroll
        for (int j = 0; j < 4; j++) {
            int tv = tern_i(w1[(co * 32 + g * 4 + j) * 9 + pos], d1);
            wd |= ((unsigned)(tv & 255)) << (8 * j);
        }
        ((int*)(ws + OFF_W1P))[idx] = (int)wd;
    } else if (idx < 9216) {                // w11p
        int i2 = idx - 4608;
        int k = i2 >> 6, co = i2 & 63;
        int pos = k >> 3, g = k & 7;
        unsigned wd = 0;
        #pragma unroll
        for (int j = 0; j < 4; j++) {
            int tv = tern_i(w11[(co * 32 + g * 4 + j) * 9 + pos], d11);
            wd |= ((unsigned)(tv & 255)) << (8 * j);
        }
        ((int*)(ws + OFF_W11P))[i2] = (int)wd;
    } else if (idx < 18432) {               // w2p [k][co], k=pos*16+g
        int i2 = idx - 9216;
        int k = i2 >> 6, co = i2 & 63;
        int pos = k >> 4, g = k & 15;
        unsigned wd = 0;
        #pragma unroll
        for (int j = 0; j < 4; j++) {
            int tv = tern_i(w2[(co * 64 + g * 4 + j) * 9 + pos], d2v);
            wd |= ((unsigned)(tv & 255)) << (8 * j);
        }
        ((int*)(ws + OFF_W2P))[i2] = (int)wd;
    } else {
        int i = idx - 18432;
        if (i < 64) {
            ((int*)(ws + OFF_B11))[i] = tern_i(b11[i], d11);
        } else if (i < 128) {
            ((int*)(ws + OFF_B1))[i - 64] = tern_i(b1[i - 64], d1);
        } else if (i < 192) {
            ((int*)(ws + OFF_B2))[i - 128] = tern_i(b2[i - 128], d2v);
        } else if (i < 216) {
            // mapw[g*3 + s], s=v+1: packed word of map1 bytes for ci = g*4..g*4+3
            int j = i - 192;                // 0..23
            int g = j / 3, s = j % 3;
            float v = (float)(s - 1);
            unsigned wd = 0;
            #pragma unroll
            for (int jj = 0; jj < 4; jj++) {
                int c = g * 4 + jj;
                float inv = __fdiv_rn(gp[c], __fsqrt_rn(__fadd_rn(vp[c], 1e-5f)));
                float sh  = __fsub_rn(bp[c], __fmul_rn(mp[c], inv));
                float z   = __fadd_rn(__fmul_rn(v, inv), sh);
                z = (z > 0.f) ? z : __fmul_rn(0.01f, z);
                wd |= ((unsigned)(tern_i(z, d1) & 255)) << (8 * jj);
            }
            ((int*)(ws + OFF_MAPW))[j] = (int)wd;
        } else if (i < 280) {
            int c = i - 216;
            float inv = __fdiv_rn(g1[c], __fsqrt_rn(__fadd_rn(v1[c], 1e-5f)));
            ((float*)(ws + OFF_S1))[c]  = inv;
            ((float*)(ws + OFF_SH1))[c] = __fsub_rn(be1[c], __fmul_rn(me1[c], inv));
        }
    }
}

// ---------------- K2: x -> packed ternary [n][y][x][g8] ----------------
__global__ __launch_bounds__(256) void k_tern_x(const float* __restrict__ x,
                                                char* __restrict__ ws) {
    float d11 = ((const float*)(ws + OFF_D))[0];
    int idx = blockIdx.x * 256 + threadIdx.x;      // 1,048,576 threads: one pixel each
    int pix = idx & 65535, n = idx >> 16;
    const float* xp = x + ((size_t)n * CIN << 16) + pix;
    int w[8];
    #pragma unroll
    for (int g = 0; g < 8; ++g) {
        unsigned wd = 0;
        #pragma unroll
        for (int j = 0; j < 4; ++j) {
            float v = xp[(size_t)(g * 4 + j) << 16];
            wd |= ((unsigned)(tern_i(v, d11) & 255)) << (8 * j);
        }
        w[g] = (int)wd;
    }
    int4* o = (int4*)(ws + OFF_XTP) + ((size_t)idx * 2);
    o[0] = make_int4(w[0], w[1], w[2], w[3]);
    o[1] = make_int4(w[4], w[5], w[6], w[7]);
}

// ---------------- K3: shortcut conv11, stride 3 -> prev (i16) ----------------
__global__ __launch_bounds__(256) void k_conv11(const char* __restrict__ ws) {
    __shared__ int wL[4608];        // [k=pos*8+g][co64]
    __shared__ int tinL[4608];      // [dy24][dx24][g8]
    int bid = blockIdx.x;
    int tx = bid % 11, ty = (bid / 11) % 11, n = bid / 121;
    int tid = threadIdx.x;
    for (int i = tid; i < 4608; i += 256) wL[i] = ((const int*)(ws + OFF_W11P))[i];
    const int* xtp = (const int*)(ws + OFF_XTP) + (size_t)n * 524288;
    int y0 = ty * 24 - 1, x0 = tx * 24 - 1;
    for (int i = tid; i < 1152; i += 256) {       // 1152 int4 = 4608 words
        int r = i / 48, cq = i % 48;
        int p = cq >> 1, gb = (cq & 1) * 4;
        int gy = y0 + r, gx = x0 + p;
        int4 v = make_int4(0, 0, 0, 0);
        if ((unsigned)gy < H && (unsigned)gx < W)
            v = *(const int4*)&xtp[(gy * 256 + gx) * 8 + gb];
        *(int4*)&tinL[(r * 24 + p) * 8 + gb] = v;
    }
    __syncthreads();
    int p2 = tid >> 3, cg = tid & 7;
    int py = p2 >> 2, px0 = (p2 & 3) * 2;
    int acc[2][8] = {};
    #pragma unroll 1
    for (int pos = 0; pos < 9; ++pos) {
        int kh = pos / 3, kw = pos - kh * 3;
        int ib = ((py * 3 + kh) * 24 + px0 * 3 + kw) * 8;
        #pragma unroll
        for (int g = 0; g < 8; ++g) {
            int a0 = tinL[ib + g];
            int a1 = tinL[ib + 24 + g];
            const int4* wp = (const int4*)&wL[(pos * 8 + g) * 64 + cg * 8];
            int4 u0 = wp[0], u1 = wp[1];
            acc[0][0] = dot4(a0, u0.x, acc[0][0]); acc[1][0] = dot4(a1, u0.x, acc[1][0]);
            acc[0][1] = dot4(a0, u0.y, acc[0][1]); acc[1][1] = dot4(a1, u0.y, acc[1][1]);
            acc[0][2] = dot4(a0, u0.z, acc[0][2]); acc[1][2] = dot4(a1, u0.z, acc[1][2]);
            acc[0][3] = dot4(a0, u0.w, acc[0][3]); acc[1][3] = dot4(a1, u0.w, acc[1][3]);
            acc[0][4] = dot4(a0, u1.x, acc[0][4]); acc[1][4] = dot4(a1, u1.x, acc[1][4]);
            acc[0][5] = dot4(a0, u1.y, acc[0][5]); acc[1][5] = dot4(a1, u1.y, acc[1][5]);
            acc[0][6] = dot4(a0, u1.z, acc[0][6]); acc[1][6] = dot4(a1, u1.z, acc[1][6]);
            acc[0][7] = dot4(a0, u1.w, acc[0][7]); acc[1][7] = dot4(a1, u1.w, acc[1][7]);
        }
    }
    const int* b11i = (const int*)(ws + OFF_B11);
    short* prev = (short*)(ws + OFF_PREV) + (size_t)n * C * PIX;
    int oh = ty * 8 + py;
    if (oh < OH) {
        #pragma unroll
        for (int j = 0; j < 2; ++j) {
            int ow = tx * 8 + px0 + j;
            if (ow < OW) {
                #pragma unroll
                for (int i = 0; i < 8; ++i) {
                    int co = cg * 8 + i;
                    prev[co * PIX + oh * OW + ow] = (short)(acc[j][i] + b11i[co]);
                }
            }
        }
    }
}

// ---------------- K4: conv1 stride 1, int8 MFMA implicit GEMM ----------------
// block = (n, 16x16 px tile); 4 waves, wave w handles rows t = 4w..4w+3, all 64 co.
// MFMA 16x16x64_i8: D[16px(x)][16co] += A[x][K] B[K][co]; K-chunk c covers pos 2c,2c+1.
__global__ __launch_bounds__(256, 2) void k_conv1(const char* __restrict__ ws) {
    __shared__ int tin[2592];     // [dy18][dx18][g8]
    __shared__ int mapw[24];
    int tid = threadIdx.x;
    int bid = blockIdx.x;
    int twx = bid & 15, twy = (bid >> 4) & 15, n = bid >> 8;
    if (tid < 24) mapw[tid] = ((const int*)(ws + OFF_MAPW))[tid];
    __syncthreads();
    const int* xtp = (const int*)(ws + OFF_XTP) + (size_t)n * 524288;
    int Y0 = twy * 16, X0 = twx * 16;
    int y0 = Y0 - 1, x0 = X0 - 1;
    // stage 18x18 halo, applying the bn/lrelu/tern byte map (OOB -> conv-input 0)
    for (int i = tid; i < 648; i += 256) {        // 648 int4 = 2592 words
        int r = i / 36, cq = i % 36;
        int p = cq >> 1, gb = (cq & 1) * 4;
        int gy = y0 + r, gx = x0 + p;
        int mw[4] = {0, 0, 0, 0};
        if ((unsigned)gy < H && (unsigned)gx < W) {
            int4 v = *(const int4*)&xtp[(gy * 256 + gx) * 8 + gb];
            #pragma unroll
            for (int j = 0; j < 4; ++j) {
                unsigned t = (j == 0) ? (unsigned)v.x : (j == 1) ? (unsigned)v.y
                           : (j == 2) ? (unsigned)v.z : (unsigned)v.w;
                unsigned nb = (t & 0x80808080u) >> 7;            // 0x01 at neg bytes
                unsigned pb = (t & 0x01010101u) & ~nb;           // 0x01 at +1 bytes
                unsigned nm = nb * 0xFFu, pm = pb * 0xFFu;
                unsigned zm = ~(nm | pm);
                int g = gb + j;
                unsigned Wn = (unsigned)mapw[g * 3 + 0];
                unsigned W0 = (unsigned)mapw[g * 3 + 1];
                unsigned Wp = (unsigned)mapw[g * 3 + 2];
                mw[j] = (int)((Wn & nm) | (W0 & zm) | (Wp & pm));
            }
        }
        *(int4*)&tin[(r * 18 + p) * 8 + gb] = make_int4(mw[0], mw[1], mw[2], mw[3]);
    }
    // B fragments (weights) -> VGPRs; lane: col c16, k-words q*4..q*4+3 of chunk
    int c16 = tid & 15, q = (tid >> 4) & 3;
    const int* w1p = (const int*)(ws + OFF_W1P);
    int bw[5][4][4];
    #pragma unroll
    for (int c = 0; c < 5; ++c) {
        int pos = 2 * c + (q >> 1);
        #pragma unroll
        for (int ct = 0; ct < 4; ++ct)
            #pragma unroll
            for (int j = 0; j < 4; ++j)
                bw[c][ct][j] = (pos < 9) ? w1p[(pos * 8 + (q & 1) * 4 + j) * 64 + ct * 16 + c16] : 0;
    }
    // epilogue constants for this lane's 4 co's
    const int* b1i = (const int*)(ws + OFF_B1);
    const float* s1 = (const float*)(ws + OFF_S1);
    const float* sh1 = (const float*)(ws + OFF_SH1);
    float d2v = ((const float*)(ws + OFF_D))[2];
    int bco[4]; float sco[4], shco[4];
    #pragma unroll
    for (int ct = 0; ct < 4; ++ct) {
        int co = ct * 16 + c16;
        bco[ct] = b1i[co]; sco[ct] = s1[co]; shco[ct] = sh1[co];
    }
    __syncthreads();
    int wv = tid >> 6;
    char* t2base = (char*)ws + OFF_T2P + ((size_t)n << 22);
    #pragma unroll
    for (int tt = 0; tt < 4; ++tt) {
        int t = wv * 4 + tt;
        // A fragments: lane row = c16 (pixel x), k-words q*4..q*4+3 of chunk
        v4i a[5];
        #pragma unroll
        for (int c = 0; c < 5; ++c) {
            int pos = 2 * c + (q >> 1);
            if (pos < 9) {
                int kh = pos / 3, kw = pos - kh * 3;
                a[c] = *(const v4i*)&tin[((t + kh) * 18 + (c16 + kw)) * 8 + (q & 1) * 4];
            } else {
                v4i z = {0, 0, 0, 0};
                a[c] = z;
            }
        }
        #pragma unroll
        for (int ct = 0; ct < 4; ++ct) {
            v4i acc = {0, 0, 0, 0};
            #pragma unroll
            for (int c = 0; c < 5; ++c) {
                v4i b = {bw[c][ct][0], bw[c][ct][1], bw[c][ct][2], bw[c][ct][3]};
                acc = __builtin_amdgcn_mfma_i32_16x16x64_i8(a[c], b, acc, 0, 0, 0);
            }
            // lane holds D rows q*4+i (pixel x), col c16 (co = ct*16+c16)
            int y = Y0 + t;
            int gw = ct * 4 + (c16 >> 2);
            #pragma unroll
            for (int i = 0; i < 4; ++i) {
                int xg = X0 + q * 4 + i;
                int vi = acc[i] + bco[ct];
                float z = __fadd_rn(__fmul_rn((float)vi, sco[ct]), shco[ct]);
                z = (z > 0.f) ? z : __fmul_rn(0.01f, z);
                signed char tv = (fabsf(z) < d2v) ? 0 : (z > 0.f ? 1 : -1);
                t2base[(((size_t)((gw << 16) + (y << 8) + xg)) << 2) + (c16 & 3)] = tv;
            }
        }
    }
}

// ---------------- K5: conv2 stride 3 fused + residual + lrelu ----------------
__global__ __launch_bounds__(256) void k_conv2(const char* __restrict__ ws,
                                               float* __restrict__ out) {
    __shared__ int wL[4608];         // [k=pos*16+g][co32 half]
    __shared__ int tinL[16 * 576];   // [g][24*24]
    int bid = blockIdx.x;
    int half = bid & 1;
    int t = bid >> 1;
    int tx = t % 11, ty = (t / 11) % 11, n = t / 121;
    int tid = threadIdx.x;
    const int* w2p = (const int*)(ws + OFF_W2P);
    for (int i = tid; i < 4608; i += 256) {
        int k = i >> 5, c = i & 31;
        wL[i] = w2p[k * 64 + half * 32 + c];
    }
    const int* t2p = (const int*)(ws + OFF_T2P) + (size_t)n * 16 * 65536;
    int y0 = ty * 24 - 1, x0 = tx * 24 - 1;
    for (int i = tid; i < 16 * 576; i += 256) {
        int g = i / 576, r = i % 576, dy = r / 24, dx = r % 24;
        int gy = y0 + dy, gx = x0 + dx;
        int v = 0;
        if ((unsigned)gy < H && (unsigned)gx < W) v = t2p[g * 65536 + gy * 256 + gx];
        tinL[i] = v;
    }
    __syncthreads();
    int p2 = tid >> 3, cg = tid & 7;
    int py = p2 >> 2, px0 = (p2 & 3) * 2;
    int acc[2][4] = {};
    #pragma unroll 1
    for (int pos = 0; pos < 9; ++pos) {
        int kh = pos / 3, kw = pos - kh * 3;
        int ib = (py * 3 + kh) * 24 + px0 * 3 + kw;
        #pragma unroll
        for (int g = 0; g < 16; ++g) {
            int a0 = tinL[g * 576 + ib];
            int a1 = tinL[g * 576 + ib + 3];
            int4 u = *(const int4*)&wL[(pos * 16 + g) * 32 + cg * 4];
            acc[0][0] = dot4(a0, u.x, acc[0][0]); acc[1][0] = dot4(a1, u.x, acc[1][0]);
            acc[0][1] = dot4(a0, u.y, acc[0][1]); acc[1][1] = dot4(a1, u.y, acc[1][1]);
            acc[0][2] = dot4(a0, u.z, acc[0][2]); acc[1][2] = dot4(a1, u.z, acc[1][2]);
            acc[0][3] = dot4(a0, u.w, acc[0][3]); acc[1][3] = dot4(a1, u.w, acc[1][3]);
        }
    }
    const int* b2i = (const int*)(ws + OFF_B2);
    const short* prev = (const short*)(ws + OFF_PREV) + (size_t)n * C * PIX;
    int oh = ty * 8 + py;
    if (oh < OH) {
        #pragma unroll
        for (int j = 0; j < 2; ++j) {
            int ow = tx * 8 + px0 + j;
            if (ow < OW) {
                #pragma unroll
                for (int i = 0; i < 4; ++i) {
                    int co = half * 32 + cg * 4 + i;
                    int a = acc[j][i] + b2i[co] + (int)prev[co * PIX + oh * OW + ow];
                    float z = (float)a;
                    out[((size_t)n * C + co) * PIX + oh * OW + ow] = (z > 0.f) ? z : __fmul_rn(0.01f, z);
                }
            }
        }
    }
}

extern "C" void kernel_launch(void* const* d_in, const int* in_sizes, int n_in,
                              void* d_out, int out_size, void* d_ws, size_t ws_size,
                              hipStream_t stream) {
    const float* x    = (const float*)d_in[0];
    const float* w11  = (const float*)d_in[1];
    const float* b11  = (const float*)d_in[2];
    const float* w1   = (const float*)d_in[3];
    const float* b1   = (const float*)d_in[4];
    const float* w2   = (const float*)d_in[5];
    const float* b2   = (const float*)d_in[6];
    const float* gp   = (const float*)d_in[7];
    const float* bp   = (const float*)d_in[8];
    const float* mp   = (const float*)d_in[9];
    const float* vp   = (const float*)d_in[10];
    const float* g1   = (const float*)d_in[11];
    const float* be1  = (const float*)d_in[12];
    const float* me1  = (const float*)d_in[13];
    const float* v1   = (const float*)d_in[14];
    char* ws = (char*)d_ws;
    float* out = (float*)d_out;

    k_absmax<<<3, 256, 0, stream>>>(w11, w1, w2, (float*)(ws + OFF_D));
    k_prep<<<74, 256, 0, stream>>>(w11, w1, w2, b11, b1, b2,
                                   gp, bp, mp, vp, g1, be1, me1, v1, ws);
    k_tern_x<<<4096, 256, 0, stream>>>(x, ws);
    k_conv11<<<121 * B, 256, 0, stream>>>(ws);
    k_conv1<<<4096, 256, 0, stream>>>(ws);
    k_conv2<<<121 * B * 2, 256, 0, stream>>>(ws, out);
}

// Round 5
// 188.264 us; speedup vs baseline: 37.7124x; 1.6400x over previous
//
#include <hip/hip_runtime.h>
#include <stdint.h>

#define B 16
#define CIN 32
#define C 64
#define H 256
#define W 256
#define OH 86
#define OW 86
#define PIX (OH*OW)   // 7396

typedef int v4i __attribute__((ext_vector_type(4)));

// ---- workspace layout (bytes) ----
#define OFF_D      0          // 3 f32: d11,d1,d2
#define OFF_MAPW   64         // 24 i32: [g8][s3] packed mapped words (s = v+1)
#define OFF_S1     256        // 64 f32
#define OFF_SH1    512        // 64 f32
#define OFF_B11    768        // 64 i32
#define OFF_B1     1024       // 64 i32
#define OFF_B2     1280       // 64 i32
#define OFF_W11P   4096       // 4608 i32, [k=pos*8+g][co64]
#define OFF_W1P    24576      // 4608 i32, [k=pos*8+g][co64]
#define OFF_W2P    45056      // 9216 i32, [k=pos*16+g][co64]
#define OFF_XTP    262144     // [n16][y256][x256][g8] i32 = 32MB (raw tern(x))
#define OFF_PREV   33816576   // i16 [n][co][pix]
#define OFF_T2P    48963584   // [n16][y256][x256][gw16] i32 = 64MB (pixel-major!)

__device__ __forceinline__ int dot4(int a, int b, int c) {
    return __builtin_amdgcn_sdot4(a, b, c, false);
}

__device__ __forceinline__ int tern_i(float t, float d) {
    return (fabsf(t) < d) ? 0 : (t > 0.f ? 1 : -1);
}

// ---------------- K0: d = 0.1 * max|w| ----------------
__global__ __launch_bounds__(256) void k_absmax(const float* w11, const float* w1,
                                                const float* w2, float* dws) {
    __shared__ float red[256];
    int b = blockIdx.x;
    const float* p = (b == 0) ? w11 : (b == 1) ? w1 : w2;
    int n = (b == 2) ? 36864 : 18432;
    float m = 0.f;
    for (int i = threadIdx.x; i < n; i += 256) m = fmaxf(m, fabsf(p[i]));
    red[threadIdx.x] = m; __syncthreads();
    for (int s = 128; s > 0; s >>= 1) {
        if (threadIdx.x < s) red[threadIdx.x] = fmaxf(red[threadIdx.x], red[threadIdx.x + s]);
        __syncthreads();
    }
    if (threadIdx.x == 0) dws[b] = __fmul_rn(0.1f, red[0]);
}

// ---------------- K1: pack weights k-major, tables ----------------
__global__ __launch_bounds__(256) void k_prep(const float* w11, const float* w1, const float* w2,
                                              const float* b11, const float* b1, const float* b2,
                                              const float* gp, const float* bp, const float* mp, const float* vp,
                                              const float* g1, const float* be1, const float* me1, const float* v1,
                                              char* ws) {
    const float* dws = (const float*)(ws + OFF_D);
    float d11 = dws[0], d1 = dws[1], d2v = dws[2];
    int idx = blockIdx.x * 256 + threadIdx.x;
    if (idx < 4608) {                       // w1p [k][co], k=pos*8+g, bytes ci=4g+j
        int k = idx >> 6, co = idx & 63;
        int pos = k >> 3, g = k & 7;
        unsigned wd = 0;
        #pragma unroll
        for (int j = 0; j < 4; j++) {
            int tv = tern_i(w1[(co * 32 + g * 4 + j) * 9 + pos], d1);
            wd |= ((unsigned)(tv & 255)) << (8 * j);
        }
        ((int*)(ws + OFF_W1P))[idx] = (int)wd;
    } else if (idx < 9216) {                // w11p
        int i2 = idx - 4608;
        int k = i2 >> 6, co = i2 & 63;
        int pos = k >> 3, g = k & 7;
        unsigned wd = 0;
        #pragma unroll
        for (int j = 0; j < 4; j++) {
            int tv = tern_i(w11[(co * 32 + g * 4 + j) * 9 + pos], d11);
            wd |= ((unsigned)(tv & 255)) << (8 * j);
        }
        ((int*)(ws + OFF_W11P))[i2] = (int)wd;
    } else if (idx < 18432) {               // w2p [k][co], k=pos*16+g
        int i2 = idx - 9216;
        int k = i2 >> 6, co = i2 & 63;
        int pos = k >> 4, g = k & 15;
        unsigned wd = 0;
        #pragma unroll
        for (int j = 0; j < 4; j++) {
            int tv = tern_i(w2[(co * 64 + g * 4 + j) * 9 + pos], d2v);
            wd |= ((unsigned)(tv & 255)) << (8 * j);
        }
        ((int*)(ws + OFF_W2P))[i2] = (int)wd;
    } else {
        int i = idx - 18432;
        if (i < 64) {
            ((int*)(ws + OFF_B11))[i] = tern_i(b11[i], d11);
        } else if (i < 128) {
            ((int*)(ws + OFF_B1))[i - 64] = tern_i(b1[i - 64], d1);
        } else if (i < 192) {
            ((int*)(ws + OFF_B2))[i - 128] = tern_i(b2[i - 128], d2v);
        } else if (i < 216) {
            // mapw[g*3 + s], s=v+1: packed word of map1 bytes for ci = g*4..g*4+3
            int j = i - 192;                // 0..23
            int g = j / 3, s = j % 3;
            float v = (float)(s - 1);
            unsigned wd = 0;
            #pragma unroll
            for (int jj = 0; jj < 4; jj++) {
                int c = g * 4 + jj;
                float inv = __fdiv_rn(gp[c], __fsqrt_rn(__fadd_rn(vp[c], 1e-5f)));
                float sh  = __fsub_rn(bp[c], __fmul_rn(mp[c], inv));
                float z   = __fadd_rn(__fmul_rn(v, inv), sh);
                z = (z > 0.f) ? z : __fmul_rn(0.01f, z);
                wd |= ((unsigned)(tern_i(z, d1) & 255)) << (8 * jj);
            }
            ((int*)(ws + OFF_MAPW))[j] = (int)wd;
        } else if (i < 280) {
            int c = i - 216;
            float inv = __fdiv_rn(g1[c], __fsqrt_rn(__fadd_rn(v1[c], 1e-5f)));
            ((float*)(ws + OFF_S1))[c]  = inv;
            ((float*)(ws + OFF_SH1))[c] = __fsub_rn(be1[c], __fmul_rn(me1[c], inv));
        }
    }
}

// ---------------- K2: x -> packed ternary [n][y][x][g8] ----------------
__global__ __launch_bounds__(256) void k_tern_x(const float* __restrict__ x,
                                                char* __restrict__ ws) {
    float d11 = ((const float*)(ws + OFF_D))[0];
    int idx = blockIdx.x * 256 + threadIdx.x;      // 1,048,576 threads: one pixel each
    int pix = idx & 65535, n = idx >> 16;
    const float* xp = x + ((size_t)n * CIN << 16) + pix;
    int w[8];
    #pragma unroll
    for (int g = 0; g < 8; ++g) {
        unsigned wd = 0;
        #pragma unroll
        for (int j = 0; j < 4; ++j) {
            float v = xp[(size_t)(g * 4 + j) << 16];
            wd |= ((unsigned)(tern_i(v, d11) & 255)) << (8 * j);
        }
        w[g] = (int)wd;
    }
    int4* o = (int4*)(ws + OFF_XTP) + ((size_t)idx * 2);
    o[0] = make_int4(w[0], w[1], w[2], w[3]);
    o[1] = make_int4(w[4], w[5], w[6], w[7]);
}

// ---------------- K3: shortcut conv11, stride 3 -> prev (i16) ----------------
__global__ __launch_bounds__(256) void k_conv11(const char* __restrict__ ws) {
    __shared__ int wL[4608];        // [k=pos*8+g][co64]
    __shared__ int tinL[4608];      // [dy24][dx24][g8]
    int bid = blockIdx.x;
    int tx = bid % 11, ty = (bid / 11) % 11, n = bid / 121;
    int tid = threadIdx.x;
    for (int i = tid; i < 4608; i += 256) wL[i] = ((const int*)(ws + OFF_W11P))[i];
    const int* xtp = (const int*)(ws + OFF_XTP) + (size_t)n * 524288;
    int y0 = ty * 24 - 1, x0 = tx * 24 - 1;
    for (int i = tid; i < 1152; i += 256) {       // 1152 int4 = 4608 words
        int r = i / 48, cq = i % 48;
        int p = cq >> 1, gb = (cq & 1) * 4;
        int gy = y0 + r, gx = x0 + p;
        int4 v = make_int4(0, 0, 0, 0);
        if ((unsigned)gy < H && (unsigned)gx < W)
            v = *(const int4*)&xtp[(gy * 256 + gx) * 8 + gb];
        *(int4*)&tinL[(r * 24 + p) * 8 + gb] = v;
    }
    __syncthreads();
    int p2 = tid >> 3, cg = tid & 7;
    int py = p2 >> 2, px0 = (p2 & 3) * 2;
    int acc[2][8] = {};
    #pragma unroll 1
    for (int pos = 0; pos < 9; ++pos) {
        int kh = pos / 3, kw = pos - kh * 3;
        int ib = ((py * 3 + kh) * 24 + px0 * 3 + kw) * 8;
        #pragma unroll
        for (int g = 0; g < 8; ++g) {
            int a0 = tinL[ib + g];
            int a1 = tinL[ib + 24 + g];
            const int4* wp = (const int4*)&wL[(pos * 8 + g) * 64 + cg * 8];
            int4 u0 = wp[0], u1 = wp[1];
            acc[0][0] = dot4(a0, u0.x, acc[0][0]); acc[1][0] = dot4(a1, u0.x, acc[1][0]);
            acc[0][1] = dot4(a0, u0.y, acc[0][1]); acc[1][1] = dot4(a1, u0.y, acc[1][1]);
            acc[0][2] = dot4(a0, u0.z, acc[0][2]); acc[1][2] = dot4(a1, u0.z, acc[1][2]);
            acc[0][3] = dot4(a0, u0.w, acc[0][3]); acc[1][3] = dot4(a1, u0.w, acc[1][3]);
            acc[0][4] = dot4(a0, u1.x, acc[0][4]); acc[1][4] = dot4(a1, u1.x, acc[1][4]);
            acc[0][5] = dot4(a0, u1.y, acc[0][5]); acc[1][5] = dot4(a1, u1.y, acc[1][5]);
            acc[0][6] = dot4(a0, u1.z, acc[0][6]); acc[1][6] = dot4(a1, u1.z, acc[1][6]);
            acc[0][7] = dot4(a0, u1.w, acc[0][7]); acc[1][7] = dot4(a1, u1.w, acc[1][7]);
        }
    }
    const int* b11i = (const int*)(ws + OFF_B11);
    short* prev = (short*)(ws + OFF_PREV) + (size_t)n * C * PIX;
    int oh = ty * 8 + py;
    if (oh < OH) {
        #pragma unroll
        for (int j = 0; j < 2; ++j) {
            int ow = tx * 8 + px0 + j;
            if (ow < OW) {
                #pragma unroll
                for (int i = 0; i < 8; ++i) {
                    int co = cg * 8 + i;
                    prev[co * PIX + oh * OW + ow] = (short)(acc[j][i] + b11i[co]);
                }
            }
        }
    }
}

// ---------------- K4: conv1 stride 1, int8 MFMA implicit GEMM ----------------
// block = (n, 16x16 px tile); 4 waves, wave w handles rows t = 4w..4w+3, all 64 co.
// MFMA 16x16x64_i8: D[16px(x)][16co] += A[x][K] B[K][co]; K-chunk c covers pos 2c,2c+1.
__global__ __launch_bounds__(256, 2) void k_conv1(const char* __restrict__ ws) {
    __shared__ int tin[2592];     // [dy18][dx18][g8]
    __shared__ int mapw[24];
    int tid = threadIdx.x;
    int bid = blockIdx.x;
    int twx = bid & 15, twy = (bid >> 4) & 15, n = bid >> 8;
    if (tid < 24) mapw[tid] = ((const int*)(ws + OFF_MAPW))[tid];
    __syncthreads();
    const int* xtp = (const int*)(ws + OFF_XTP) + (size_t)n * 524288;
    int Y0 = twy * 16, X0 = twx * 16;
    int y0 = Y0 - 1, x0 = X0 - 1;
    // stage 18x18 halo, applying the bn/lrelu/tern byte map (OOB -> conv-input 0)
    for (int i = tid; i < 648; i += 256) {        // 648 int4 = 2592 words
        int r = i / 36, cq = i % 36;
        int p = cq >> 1, gb = (cq & 1) * 4;
        int gy = y0 + r, gx = x0 + p;
        int mw[4] = {0, 0, 0, 0};
        if ((unsigned)gy < H && (unsigned)gx < W) {
            int4 v = *(const int4*)&xtp[(gy * 256 + gx) * 8 + gb];
            #pragma unroll
            for (int j = 0; j < 4; ++j) {
                unsigned t = (j == 0) ? (unsigned)v.x : (j == 1) ? (unsigned)v.y
                           : (j == 2) ? (unsigned)v.z : (unsigned)v.w;
                unsigned nb = (t & 0x80808080u) >> 7;            // 0x01 at neg bytes
                unsigned pb = (t & 0x01010101u) & ~nb;           // 0x01 at +1 bytes
                unsigned nm = nb * 0xFFu, pm = pb * 0xFFu;
                unsigned zm = ~(nm | pm);
                int g = gb + j;
                unsigned Wn = (unsigned)mapw[g * 3 + 0];
                unsigned W0 = (unsigned)mapw[g * 3 + 1];
                unsigned Wp = (unsigned)mapw[g * 3 + 2];
                mw[j] = (int)((Wn & nm) | (W0 & zm) | (Wp & pm));
            }
        }
        *(int4*)&tin[(r * 18 + p) * 8 + gb] = make_int4(mw[0], mw[1], mw[2], mw[3]);
    }
    // B fragments (weights) -> VGPRs; lane: col c16, k-words q*4..q*4+3 of chunk
    int c16 = tid & 15, q = (tid >> 4) & 3;
    const int* w1p = (const int*)(ws + OFF_W1P);
    int bw[5][4][4];
    #pragma unroll
    for (int c = 0; c < 5; ++c) {
        int pos = 2 * c + (q >> 1);
        #pragma unroll
        for (int ct = 0; ct < 4; ++ct)
            #pragma unroll
            for (int j = 0; j < 4; ++j)
                bw[c][ct][j] = (pos < 9) ? w1p[(pos * 8 + (q & 1) * 4 + j) * 64 + ct * 16 + c16] : 0;
    }
    // epilogue constants for this lane's 4 co's
    const int* b1i = (const int*)(ws + OFF_B1);
    const float* s1 = (const float*)(ws + OFF_S1);
    const float* sh1 = (const float*)(ws + OFF_SH1);
    float d2v = ((const float*)(ws + OFF_D))[2];
    int bco[4]; float sco[4], shco[4];
    #pragma unroll
    for (int ct = 0; ct < 4; ++ct) {
        int co = ct * 16 + c16;
        bco[ct] = b1i[co]; sco[ct] = s1[co]; shco[ct] = sh1[co];
    }
    __syncthreads();
    int wv = tid >> 6;
    char* t2base = (char*)ws + OFF_T2P + ((size_t)n << 22);
    #pragma unroll
    for (int tt = 0; tt < 4; ++tt) {
        int t = wv * 4 + tt;
        // A fragments: lane row = c16 (pixel x), k-words q*4..q*4+3 of chunk
        v4i a[5];
        #pragma unroll
        for (int c = 0; c < 5; ++c) {
            int pos = 2 * c + (q >> 1);
            if (pos < 9) {
                int kh = pos / 3, kw = pos - kh * 3;
                a[c] = *(const v4i*)&tin[((t + kh) * 18 + (c16 + kw)) * 8 + (q & 1) * 4];
            } else {
                v4i z = {0, 0, 0, 0};
                a[c] = z;
            }
        }
        #pragma unroll
        for (int ct = 0; ct < 4; ++ct) {
            v4i acc = {0, 0, 0, 0};
            #pragma unroll
            for (int c = 0; c < 5; ++c) {
                v4i b = {bw[c][ct][0], bw[c][ct][1], bw[c][ct][2], bw[c][ct][3]};
                acc = __builtin_amdgcn_mfma_i32_16x16x64_i8(a[c], b, acc, 0, 0, 0);
            }
            // lane holds D rows q*4+i (pixel x), col c16 (co = ct*16+c16)
            int y = Y0 + t;
            int gw = ct * 4 + (c16 >> 2);
            #pragma unroll
            for (int i = 0; i < 4; ++i) {
                int xg = X0 + q * 4 + i;
                int vi = acc[i] + bco[ct];
                float z = __fadd_rn(__fmul_rn((float)vi, sco[ct]), shco[ct]);
                z = (z > 0.f) ? z : __fmul_rn(0.01f, z);
                signed char tv = (fabsf(z) < d2v) ? 0 : (z > 0.f ? 1 : -1);
                // pixel-major t2p: [pixel][gw] bytes
                t2base[(((size_t)((y << 8) + xg)) << 6) + (gw << 2) + (c16 & 3)] = tv;
            }
        }
    }
}

// ---------------- K5: conv2 stride 3, int8 MFMA implicit GEMM, fused ----------------
// grid: 16n x 58 tiles of 128 px. Block 4 waves: wv&1 = co-half (32 co), wv>>1 = px-half (64 px).
// Wave: 4 pixel-groups of 16 px; per pg: 9 A-loads (16B global) + 2 co-tiles x 9 MFMA.
__global__ __launch_bounds__(256) void k_conv2(const char* __restrict__ ws,
                                               float* __restrict__ out) {
    int tid = threadIdx.x;
    int bid = blockIdx.x;
    int tile = bid % 58, n = bid / 58;
    int c16 = tid & 15, q = (tid >> 4) & 3, wv = tid >> 6;
    int h = wv & 1, ph = wv >> 1;
    const int* w2p = (const int*)(ws + OFF_W2P);
    int bw[9][2][4];
    #pragma unroll
    for (int pos = 0; pos < 9; ++pos)
        #pragma unroll
        for (int cot = 0; cot < 2; ++cot)
            #pragma unroll
            for (int j = 0; j < 4; ++j)
                bw[pos][cot][j] = w2p[(pos * 16 + q * 4 + j) * 64 + h * 32 + cot * 16 + c16];
    const char* t2 = (const char*)ws + OFF_T2P + ((size_t)n << 22);
    const int* b2i = (const int*)(ws + OFF_B2);
    int bco[2] = { b2i[h * 32 + c16], b2i[h * 32 + 16 + c16] };
    const short* prev = (const short*)(ws + OFF_PREV) + (size_t)n * C * PIX;
    float* outn = out + (size_t)n * C * PIX;
    int pbase = tile * 128 + ph * 64;
    #pragma unroll 1
    for (int pg = 0; pg < 4; ++pg) {
        int pA = pbase + pg * 16 + c16;
        int oh = pA / 86, ow = pA - oh * 86;
        v4i a[9];
        #pragma unroll
        for (int pos = 0; pos < 9; ++pos) {
            int kh = pos / 3, kw = pos - kh * 3;
            int ih = oh * 3 - 1 + kh, iw = ow * 3 - 1 + kw;
            v4i z = {0, 0, 0, 0};
            if (pA < PIX && (unsigned)ih < H && (unsigned)iw < W)
                z = *(const v4i*)(t2 + (((size_t)((ih << 8) + iw)) << 6) + (q << 4));
            a[pos] = z;
        }
        #pragma unroll
        for (int cot = 0; cot < 2; ++cot) {
            v4i acc = {0, 0, 0, 0};
            #pragma unroll
            for (int pos = 0; pos < 9; ++pos) {
                v4i b = {bw[pos][cot][0], bw[pos][cot][1], bw[pos][cot][2], bw[pos][cot][3]};
                acc = __builtin_amdgcn_mfma_i32_16x16x64_i8(a[pos], b, acc, 0, 0, 0);
            }
            int co = h * 32 + cot * 16 + c16;
            int p0 = pbase + pg * 16 + q * 4;
            #pragma unroll
            for (int i = 0; i < 4; ++i) {
                int p = p0 + i;
                if (p < PIX) {
                    int v = acc[i] + bco[cot] + (int)prev[co * PIX + p];
                    float z2 = (float)v;
                    outn[(size_t)co * PIX + p] = (z2 > 0.f) ? z2 : __fmul_rn(0.01f, z2);
                }
            }
        }
    }
}

extern "C" void kernel_launch(void* const* d_in, const int* in_sizes, int n_in,
                              void* d_out, int out_size, void* d_ws, size_t ws_size,
                              hipStream_t stream) {
    const float* x    = (const float*)d_in[0];
    const float* w11  = (const float*)d_in[1];
    const float* b11  = (const float*)d_in[2];
    const float* w1   = (const float*)d_in[3];
    const float* b1   = (const float*)d_in[4];
    const float* w2   = (const float*)d_in[5];
    const float* b2   = (const float*)d_in[6];
    const float* gp   = (const float*)d_in[7];
    const float* bp   = (const float*)d_in[8];
    const float* mp   = (const float*)d_in[9];
    const float* vp   = (const float*)d_in[10];
    const float* g1   = (const float*)d_in[11];
    const float* be1  = (const float*)d_in[12];
    const float* me1  = (const float*)d_in[13];
    const float* v1   = (const float*)d_in[14];
    char* ws = (char*)d_ws;
    float* out = (float*)d_out;

    k_absmax<<<3, 256, 0, stream>>>(w11, w1, w2, (float*)(ws + OFF_D));
    k_prep<<<74, 256, 0, stream>>>(w11, w1, w2, b11, b1, b2,
                                   gp, bp, mp, vp, g1, be1, me1, v1, ws);
    k_tern_x<<<4096, 256, 0, stream>>>(x, ws);
    k_conv11<<<121 * B, 256, 0, stream>>>(ws);
    k_conv1<<<4096, 256, 0, stream>>>(ws);
    k_conv2<<<58 * B, 256, 0, stream>>>(ws, out);
}

// Round 6
// 152.469 us; speedup vs baseline: 46.5660x; 1.2348x over previous
//
#include <hip/hip_runtime.h>
#include <stdint.h>

#define B 16
#define CIN 32
#define C 64
#define H 256
#define W 256
#define OH 86
#define OW 86
#define PIX (OH*OW)   // 7396

typedef int v4i __attribute__((ext_vector_type(4)));

// ---- workspace layout (bytes) ----
#define OFF_D      0          // 3 u32: bit patterns of max|w11|, max|w1|, max|w2|
#define OFF_MAPW   64         // 24 i32: [g8][s3] packed mapped words (s = v+1)
#define OFF_S1     256        // 64 f32
#define OFF_SH1    512        // 64 f32
#define OFF_B11    768        // 64 i32
#define OFF_B1     1024       // 64 i32
#define OFF_B2     1280       // 64 i32
#define OFF_W11P   4096       // 4608 i32: w11q [pos9][hcot4][c16 16][g8]
#define OFF_W1P    24576      // 4608 i32: w1p  [k=pos*8+g][co64] (conv1 layout)
#define OFF_W2P    45056      // 9216 i32: w2q  [pos9][hcot4][c16 16][g16]
#define OFF_XTP    262144     // [n16][y256][x256][g8] i32 = 32MB (raw tern(x))
#define OFF_PREV   33816576   // i16 [n][co][pix]
#define OFF_T2P    48963584   // [n16][y256][x256][co64 bytes] = 64MB (pixel-major)

__device__ __forceinline__ int tern_i(float t, float d) {
    return (fabsf(t) < d) ? 0 : (t > 0.f ? 1 : -1);
}

// ---------------- K-1: zero the absmax slots ----------------
__global__ void k_zero(unsigned* d) {
    if (threadIdx.x < 3) d[threadIdx.x] = 0u;
}

// ---------------- K0: max|w| via bitwise atomicMax ----------------
__global__ __launch_bounds__(256) void k_absmax(const float* w11, const float* w1,
                                                const float* w2, unsigned* dws) {
    __shared__ unsigned red[256];
    int b = blockIdx.x >> 4, sub = blockIdx.x & 15;
    const float* p = (b == 0) ? w11 : (b == 1) ? w1 : w2;
    int n = (b == 2) ? 36864 : 18432;
    int chunk = (n + 15) >> 4;
    int lo = sub * chunk, hi = min(lo + chunk, n);
    unsigned m = 0;
    for (int i = lo + threadIdx.x; i < hi; i += 256)
        m = max(m, __float_as_uint(fabsf(p[i])));
    red[threadIdx.x] = m; __syncthreads();
    for (int s = 128; s > 0; s >>= 1) {
        if (threadIdx.x < s) red[threadIdx.x] = max(red[threadIdx.x], red[threadIdx.x + s]);
        __syncthreads();
    }
    if (threadIdx.x == 0) atomicMax(&dws[b], red[0]);
}

// ---------------- K1: pack weights, tables ----------------
__global__ __launch_bounds__(256) void k_prep(const float* w11, const float* w1, const float* w2,
                                              const float* b11, const float* b1, const float* b2,
                                              const float* gp, const float* bp, const float* mp, const float* vp,
                                              const float* g1, const float* be1, const float* me1, const float* v1,
                                              char* ws) {
    const unsigned* dw = (const unsigned*)(ws + OFF_D);
    float d11 = __fmul_rn(0.1f, __uint_as_float(dw[0]));
    float d1  = __fmul_rn(0.1f, __uint_as_float(dw[1]));
    float d2v = __fmul_rn(0.1f, __uint_as_float(dw[2]));
    int idx = blockIdx.x * 256 + threadIdx.x;
    if (idx < 4608) {                       // w1p [k=pos*8+g][co64]  (conv1)
        int k = idx >> 6, co = idx & 63;
        int pos = k >> 3, g = k & 7;
        unsigned wd = 0;
        #pragma unroll
        for (int j = 0; j < 4; j++) {
            int tv = tern_i(w1[(co * 32 + g * 4 + j) * 9 + pos], d1);
            wd |= ((unsigned)(tv & 255)) << (8 * j);
        }
        ((int*)(ws + OFF_W1P))[idx] = (int)wd;
    } else if (idx < 9216) {                // w11q [pos][hcot][c16][g8]
        int i2 = idx - 4608;
        int g = i2 & 7, c16 = (i2 >> 3) & 15, hcot = (i2 >> 7) & 3, pos = i2 >> 9;
        int co = hcot * 16 + c16;
        unsigned wd = 0;
        #pragma unroll
        for (int j = 0; j < 4; j++) {
            int tv = tern_i(w11[(co * 32 + g * 4 + j) * 9 + pos], d11);
            wd |= ((unsigned)(tv & 255)) << (8 * j);
        }
        ((int*)(ws + OFF_W11P))[i2] = (int)wd;
    } else if (idx < 18432) {               // w2q [pos][hcot][c16][g16]
        int i2 = idx - 9216;
        int g = i2 & 15, c16 = (i2 >> 4) & 15, hcot = (i2 >> 8) & 3, pos = i2 >> 10;
        int co = hcot * 16 + c16;
        unsigned wd = 0;
        #pragma unroll
        for (int j = 0; j < 4; j++) {
            int tv = tern_i(w2[(co * 64 + g * 4 + j) * 9 + pos], d2v);
            wd |= ((unsigned)(tv & 255)) << (8 * j);
        }
        ((int*)(ws + OFF_W2P))[i2] = (int)wd;
    } else {
        int i = idx - 18432;
        if (i < 64) {
            ((int*)(ws + OFF_B11))[i] = tern_i(b11[i], d11);
        } else if (i < 128) {
            ((int*)(ws + OFF_B1))[i - 64] = tern_i(b1[i - 64], d1);
        } else if (i < 192) {
            ((int*)(ws + OFF_B2))[i - 128] = tern_i(b2[i - 128], d2v);
        } else if (i < 216) {
            int j = i - 192;                // 0..23
            int g = j / 3, s = j % 3;
            float v = (float)(s - 1);
            unsigned wd = 0;
            #pragma unroll
            for (int jj = 0; jj < 4; jj++) {
                int c = g * 4 + jj;
                float inv = __fdiv_rn(gp[c], __fsqrt_rn(__fadd_rn(vp[c], 1e-5f)));
                float sh  = __fsub_rn(bp[c], __fmul_rn(mp[c], inv));
                float z   = __fadd_rn(__fmul_rn(v, inv), sh);
                z = (z > 0.f) ? z : __fmul_rn(0.01f, z);
                wd |= ((unsigned)(tern_i(z, d1) & 255)) << (8 * jj);
            }
            ((int*)(ws + OFF_MAPW))[j] = (int)wd;
        } else if (i < 280) {
            int c = i - 216;
            float inv = __fdiv_rn(g1[c], __fsqrt_rn(__fadd_rn(v1[c], 1e-5f)));
            ((float*)(ws + OFF_S1))[c]  = inv;
            ((float*)(ws + OFF_SH1))[c] = __fsub_rn(be1[c], __fmul_rn(me1[c], inv));
        }
    }
}

// ---------------- K2: x -> packed ternary [n][y][x][g8] ----------------
__global__ __launch_bounds__(256) void k_tern_x(const float* __restrict__ x,
                                                char* __restrict__ ws) {
    float d11 = __fmul_rn(0.1f, __uint_as_float(((const unsigned*)(ws + OFF_D))[0]));
    int idx = blockIdx.x * 256 + threadIdx.x;      // 1,048,576 threads: one pixel each
    int pix = idx & 65535, n = idx >> 16;
    const float* xp = x + ((size_t)n * CIN << 16) + pix;
    int w[8];
    #pragma unroll
    for (int g = 0; g < 8; ++g) {
        unsigned wd = 0;
        #pragma unroll
        for (int j = 0; j < 4; ++j) {
            float v = xp[(size_t)(g * 4 + j) << 16];
            wd |= ((unsigned)(tern_i(v, d11) & 255)) << (8 * j);
        }
        w[g] = (int)wd;
    }
    int4* o = (int4*)(ws + OFF_XTP) + ((size_t)idx * 2);
    o[0] = make_int4(w[0], w[1], w[2], w[3]);
    o[1] = make_int4(w[4], w[5], w[6], w[7]);
}

// ---------------- K3: shortcut conv11, stride 3, int8 MFMA -> prev (i16) ----------------
// grid 116 tiles x 16n; block 4 waves: h = co-half, ph = px-half; wave: 32px x 32co.
__global__ __launch_bounds__(256) void k_conv11(const char* __restrict__ ws) {
    int tid = threadIdx.x, bid = blockIdx.x;
    int tile = bid % 116, n = bid / 116;
    int c16 = tid & 15, q = (tid >> 4) & 3, wv = tid >> 6;
    int h = wv & 1, ph = wv >> 1;
    const int* w11q = (const int*)(ws + OFF_W11P);
    const int* xtp = (const int*)(ws + OFF_XTP) + (size_t)n * 524288;
    const int* b11i = (const int*)(ws + OFF_B11);
    int bco[2] = { b11i[h * 32 + c16], b11i[h * 32 + 16 + c16] };
    short* prev = (short*)(ws + OFF_PREV) + (size_t)n * C * PIX;
    int pbase = tile * 64;
    #pragma unroll
    for (int pgi = 0; pgi < 2; ++pgi) {
        int pg = ph * 2 + pgi;
        int pA = pbase + pg * 16 + c16;
        int oh = pA / 86, ow = pA - oh * 86;
        v4i a[5];
        #pragma unroll
        for (int c = 0; c < 5; ++c) {
            int pos = 2 * c + (q >> 1);
            v4i z = {0, 0, 0, 0};
            if (pos < 9) {
                int kh = pos / 3, kw = pos - kh * 3;
                int ih = oh * 3 - 1 + kh, iw = ow * 3 - 1 + kw;
                if (pA < PIX && (unsigned)ih < H && (unsigned)iw < W)
                    z = *(const v4i*)&xtp[(ih * 256 + iw) * 8 + (q & 1) * 4];
            }
            a[c] = z;
        }
        #pragma unroll
        for (int cot = 0; cot < 2; ++cot) {
            int hc = h * 2 + cot;
            v4i acc = {0, 0, 0, 0};
            #pragma unroll
            for (int c = 0; c < 5; ++c) {
                int pos = 2 * c + (q >> 1);
                v4i b = {0, 0, 0, 0};
                if (pos < 9)
                    b = *(const v4i*)&w11q[((pos * 4 + hc) * 16 + c16) * 8 + (q & 1) * 4];
                acc = __builtin_amdgcn_mfma_i32_16x16x64_i8(a[c], b, acc, 0, 0, 0);
            }
            int co = h * 32 + cot * 16 + c16;
            int p0 = pbase + pg * 16 + q * 4;
            #pragma unroll
            for (int i = 0; i < 4; ++i) {
                int p = p0 + i;
                if (p < PIX) prev[co * PIX + p] = (short)(acc[i] + bco[cot]);
            }
        }
    }
}

// ---------------- K4: conv1 stride 1, int8 MFMA implicit GEMM ----------------
__global__ __launch_bounds__(256, 2) void k_conv1(const char* __restrict__ ws) {
    __shared__ int tin[2592];     // [dy18][dx18][g8]
    __shared__ int mapw[24];
    int tid = threadIdx.x;
    int bid = blockIdx.x;
    int twx = bid & 15, twy = (bid >> 4) & 15, n = bid >> 8;
    if (tid < 24) mapw[tid] = ((const int*)(ws + OFF_MAPW))[tid];
    __syncthreads();
    const int* xtp = (const int*)(ws + OFF_XTP) + (size_t)n * 524288;
    int Y0 = twy * 16, X0 = twx * 16;
    int y0 = Y0 - 1, x0 = X0 - 1;
    // stage 18x18 halo, applying the bn/lrelu/tern byte map (OOB -> conv-input 0)
    for (int i = tid; i < 648; i += 256) {        // 648 int4 = 2592 words
        int r = i / 36, cq = i % 36;
        int p = cq >> 1, gb = (cq & 1) * 4;
        int gy = y0 + r, gx = x0 + p;
        int mw[4] = {0, 0, 0, 0};
        if ((unsigned)gy < H && (unsigned)gx < W) {
            int4 v = *(const int4*)&xtp[(gy * 256 + gx) * 8 + gb];
            #pragma unroll
            for (int j = 0; j < 4; ++j) {
                unsigned t = (j == 0) ? (unsigned)v.x : (j == 1) ? (unsigned)v.y
                           : (j == 2) ? (unsigned)v.z : (unsigned)v.w;
                unsigned nb = (t & 0x80808080u) >> 7;
                unsigned pb = (t & 0x01010101u) & ~nb;
                unsigned nm = nb * 0xFFu, pm = pb * 0xFFu;
                unsigned zm = ~(nm | pm);
                int g = gb + j;
                unsigned Wn = (unsigned)mapw[g * 3 + 0];
                unsigned W0 = (unsigned)mapw[g * 3 + 1];
                unsigned Wp = (unsigned)mapw[g * 3 + 2];
                mw[j] = (int)((Wn & nm) | (W0 & zm) | (Wp & pm));
            }
        }
        *(int4*)&tin[(r * 18 + p) * 8 + gb] = make_int4(mw[0], mw[1], mw[2], mw[3]);
    }
    int c16 = tid & 15, q = (tid >> 4) & 3;
    const int* w1p = (const int*)(ws + OFF_W1P);
    int bw[5][4][4];
    #pragma unroll
    for (int c = 0; c < 5; ++c) {
        int pos = 2 * c + (q >> 1);
        #pragma unroll
        for (int ct = 0; ct < 4; ++ct)
            #pragma unroll
            for (int j = 0; j < 4; ++j)
                bw[c][ct][j] = (pos < 9) ? w1p[(pos * 8 + (q & 1) * 4 + j) * 64 + ct * 16 + c16] : 0;
    }
    const int* b1i = (const int*)(ws + OFF_B1);
    const float* s1 = (const float*)(ws + OFF_S1);
    const float* sh1 = (const float*)(ws + OFF_SH1);
    float d2v = __fmul_rn(0.1f, __uint_as_float(((const unsigned*)(ws + OFF_D))[2]));
    int bco[4]; float sco[4], shco[4];
    #pragma unroll
    for (int ct = 0; ct < 4; ++ct) {
        int co = ct * 16 + c16;
        bco[ct] = b1i[co]; sco[ct] = s1[co]; shco[ct] = sh1[co];
    }
    __syncthreads();
    int wv = tid >> 6;
    char* t2base = (char*)ws + OFF_T2P + ((size_t)n << 22);
    #pragma unroll
    for (int tt = 0; tt < 4; ++tt) {
        int t = wv * 4 + tt;
        v4i a[5];
        #pragma unroll
        for (int c = 0; c < 5; ++c) {
            int pos = 2 * c + (q >> 1);
            if (pos < 9) {
                int kh = pos / 3, kw = pos - kh * 3;
                a[c] = *(const v4i*)&tin[((t + kh) * 18 + (c16 + kw)) * 8 + (q & 1) * 4];
            } else {
                v4i z = {0, 0, 0, 0};
                a[c] = z;
            }
        }
        #pragma unroll
        for (int ct = 0; ct < 4; ++ct) {
            v4i acc = {0, 0, 0, 0};
            #pragma unroll
            for (int c = 0; c < 5; ++c) {
                v4i b = {bw[c][ct][0], bw[c][ct][1], bw[c][ct][2], bw[c][ct][3]};
                acc = __builtin_amdgcn_mfma_i32_16x16x64_i8(a[c], b, acc, 0, 0, 0);
            }
            int y = Y0 + t;
            int gw = ct * 4 + (c16 >> 2);
            #pragma unroll
            for (int i = 0; i < 4; ++i) {
                int xg = X0 + q * 4 + i;
                int vi = acc[i] + bco[ct];
                float z = __fadd_rn(__fmul_rn((float)vi, sco[ct]), shco[ct]);
                z = (z > 0.f) ? z : __fmul_rn(0.01f, z);
                signed char tv = (fabsf(z) < d2v) ? 0 : (z > 0.f ? 1 : -1);
                t2base[(((size_t)((y << 8) + xg)) << 6) + (gw << 2) + (c16 & 3)] = tv;
            }
        }
    }
}

// ---------------- K5: conv2 stride 3, int8 MFMA, weights from L2 ----------------
// grid 116 tiles x 16n; block 4 waves: h = co-half, ph = px-half; wave: 32px x 32co.
__global__ __launch_bounds__(256) void k_conv2(const char* __restrict__ ws,
                                               float* __restrict__ out) {
    int tid = threadIdx.x, bid = blockIdx.x;
    int tile = bid % 116, n = bid / 116;
    int c16 = tid & 15, q = (tid >> 4) & 3, wv = tid >> 6;
    int h = wv & 1, ph = wv >> 1;
    const int* w2q = (const int*)(ws + OFF_W2P);
    const char* t2 = (const char*)ws + OFF_T2P + ((size_t)n << 22);
    const int* b2i = (const int*)(ws + OFF_B2);
    int bco[2] = { b2i[h * 32 + c16], b2i[h * 32 + 16 + c16] };
    const short* prev = (const short*)(ws + OFF_PREV) + (size_t)n * C * PIX;
    float* outn = out + (size_t)n * C * PIX;
    int pbase = tile * 64;
    #pragma unroll
    for (int pgi = 0; pgi < 2; ++pgi) {
        int pg = ph * 2 + pgi;
        int pA = pbase + pg * 16 + c16;
        int oh = pA / 86, ow = pA - oh * 86;
        v4i a[9];
        #pragma unroll
        for (int pos = 0; pos < 9; ++pos) {
            int kh = pos / 3, kw = pos - kh * 3;
            int ih = oh * 3 - 1 + kh, iw = ow * 3 - 1 + kw;
            v4i z = {0, 0, 0, 0};
            if (pA < PIX && (unsigned)ih < H && (unsigned)iw < W)
                z = *(const v4i*)(t2 + (((size_t)((ih << 8) + iw)) << 6) + (q << 4));
            a[pos] = z;
        }
        #pragma unroll
        for (int cot = 0; cot < 2; ++cot) {
            int hc = h * 2 + cot;
            v4i acc = {0, 0, 0, 0};
            #pragma unroll
            for (int pos = 0; pos < 9; ++pos) {
                v4i b = *(const v4i*)&w2q[((pos * 4 + hc) * 16 + c16) * 16 + q * 4];
                acc = __builtin_amdgcn_mfma_i32_16x16x64_i8(a[pos], b, acc, 0, 0, 0);
            }
            int co = h * 32 + cot * 16 + c16;
            int p0 = pbase + pg * 16 + q * 4;
            #pragma unroll
            for (int i = 0; i < 4; ++i) {
                int p = p0 + i;
                if (p < PIX) {
                    int v = acc[i] + bco[cot] + (int)prev[co * PIX + p];
                    float z2 = (float)v;
                    outn[(size_t)co * PIX + p] = (z2 > 0.f) ? z2 : __fmul_rn(0.01f, z2);
                }
            }
        }
    }
}

extern "C" void kernel_launch(void* const* d_in, const int* in_sizes, int n_in,
                              void* d_out, int out_size, void* d_ws, size_t ws_size,
                              hipStream_t stream) {
    const float* x    = (const float*)d_in[0];
    const float* w11  = (const float*)d_in[1];
    const float* b11  = (const float*)d_in[2];
    const float* w1   = (const float*)d_in[3];
    const float* b1   = (const float*)d_in[4];
    const float* w2   = (const float*)d_in[5];
    const float* b2   = (const float*)d_in[6];
    const float* gp   = (const float*)d_in[7];
    const float* bp   = (const float*)d_in[8];
    const float* mp   = (const float*)d_in[9];
    const float* vp   = (const float*)d_in[10];
    const float* g1   = (const float*)d_in[11];
    const float* be1  = (const float*)d_in[12];
    const float* me1  = (const float*)d_in[13];
    const float* v1   = (const float*)d_in[14];
    char* ws = (char*)d_ws;
    float* out = (float*)d_out;

    k_zero<<<1, 64, 0, stream>>>((unsigned*)(ws + OFF_D));
    k_absmax<<<48, 256, 0, stream>>>(w11, w1, w2, (unsigned*)(ws + OFF_D));
    k_prep<<<74, 256, 0, stream>>>(w11, w1, w2, b11, b1, b2,
                                   gp, bp, mp, vp, g1, be1, me1, v1, ws);
    k_tern_x<<<4096, 256, 0, stream>>>(x, ws);
    k_conv11<<<116 * B, 256, 0, stream>>>(ws);
    k_conv1<<<4096, 256, 0, stream>>>(ws);
    k_conv2<<<116 * B, 256, 0, stream>>>(ws, out);
}

// Round 8
// 149.665 us; speedup vs baseline: 47.4385x; 1.0187x over previous
//
#include <hip/hip_runtime.h>
#include <stdint.h>

#define B 16
#define CIN 32
#define C 64
#define H 256
#define W 256
#define OH 86
#define OW 86
#define PIX (OH*OW)   // 7396

typedef int v4i __attribute__((ext_vector_type(4)));

// ---- workspace layout (bytes) ----
#define OFF_D      0          // 3 u32: bit patterns of max|w11|, max|w1|, max|w2|
#define OFF_MAPW   64         // 24 i32: [g8][s3] packed mapped words (s = v+1)
#define OFF_S1     256        // 64 f32
#define OFF_SH1    512        // 64 f32
#define OFF_B11    768        // 64 i32
#define OFF_B1     1024       // 64 i32
#define OFF_B2     1280       // 64 i32
#define OFF_W11R   4096       // 4608 i32: [pos9][q1 2][cot4][c16][j4]
#define OFF_W1R    24576      // 4608 i32: [pos9][q1 2][h2][cot2][c16][j4]
#define OFF_W2R    45056      // 9216 i32: [pos9][h2][q1 2][cot4][c16][j4]
#define OFF_XTP    262144     // [n16][pix 65536][32B] raw tern(x)   = 32MB
#define OFF_XMAP   33816576   // [n16][pix 65536][32B] mapped, halves swizzled by f(gx) = 32MB

__device__ __forceinline__ int tern_i(float t, float d) {
    return (fabsf(t) < d) ? 0 : (t > 0.f ? 1 : -1);
}

// ---------------- K-1: zero the absmax slots ----------------
__global__ void k_zero(unsigned* d) {
    if (threadIdx.x < 3) d[threadIdx.x] = 0u;
}

// ---------------- K0: max|w| via bitwise atomicMax ----------------
__global__ __launch_bounds__(256) void k_absmax(const float* w11, const float* w1,
                                                const float* w2, unsigned* dws) {
    __shared__ unsigned red[256];
    int b = blockIdx.x >> 4, sub = blockIdx.x & 15;
    const float* p = (b == 0) ? w11 : (b == 1) ? w1 : w2;
    int n = (b == 2) ? 36864 : 18432;
    int chunk = (n + 15) >> 4;
    int lo = sub * chunk, hi = min(lo + chunk, n);
    unsigned m = 0;
    for (int i = lo + threadIdx.x; i < hi; i += 256)
        m = max(m, __float_as_uint(fabsf(p[i])));
    red[threadIdx.x] = m; __syncthreads();
    for (int s = 128; s > 0; s >>= 1) {
        if (threadIdx.x < s) red[threadIdx.x] = max(red[threadIdx.x], red[threadIdx.x + s]);
        __syncthreads();
    }
    if (threadIdx.x == 0) atomicMax(&dws[b], red[0]);
}

// ---------------- K1: pack weights, tables ----------------
__global__ __launch_bounds__(256) void k_prep(const float* w11, const float* w1, const float* w2,
                                              const float* b11, const float* b1, const float* b2,
                                              const float* gp, const float* bp, const float* mp, const float* vp,
                                              const float* g1, const float* be1, const float* me1, const float* v1,
                                              char* ws) {
    const unsigned* dw = (const unsigned*)(ws + OFF_D);
    float d11 = __fmul_rn(0.1f, __uint_as_float(dw[0]));
    float d1  = __fmul_rn(0.1f, __uint_as_float(dw[1]));
    float d2v = __fmul_rn(0.1f, __uint_as_float(dw[2]));
    int idx = blockIdx.x * 256 + threadIdx.x;
    if (idx < 4608) {                       // w1r [pos][q1][h][cot][c16][j]
        int j = idx & 3, c16 = (idx >> 2) & 15, cot = (idx >> 6) & 1;
        int h = (idx >> 7) & 1, q1 = (idx >> 8) & 1, pos = idx >> 9;
        int co = h * 32 + cot * 16 + c16;
        unsigned wd = 0;
        #pragma unroll
        for (int jj = 0; jj < 4; jj++) {
            int ci = q1 * 16 + j * 4 + jj;
            int tv = tern_i(w1[(co * 32 + ci) * 9 + pos], d1);
            wd |= ((unsigned)(tv & 255)) << (8 * jj);
        }
        ((int*)(ws + OFF_W1R))[idx] = (int)wd;
    } else if (idx < 9216) {                // w11r [pos][q1][cot4][c16][j]
        int i2 = idx - 4608;
        int j = i2 & 3, c16 = (i2 >> 2) & 15, cot = (i2 >> 6) & 3;
        int q1 = (i2 >> 8) & 1, pos = i2 >> 9;
        int co = cot * 16 + c16;
        unsigned wd = 0;
        #pragma unroll
        for (int jj = 0; jj < 4; jj++) {
            int ci = q1 * 16 + j * 4 + jj;
            int tv = tern_i(w11[(co * 32 + ci) * 9 + pos], d11);
            wd |= ((unsigned)(tv & 255)) << (8 * jj);
        }
        ((int*)(ws + OFF_W11R))[i2] = (int)wd;
    } else if (idx < 18432) {               // w2r [pos][h][q1][cot4][c16][j]
        int i2 = idx - 9216;
        int j = i2 & 3, c16 = (i2 >> 2) & 15, cot = (i2 >> 6) & 3;
        int q1 = (i2 >> 8) & 1, h = (i2 >> 9) & 1, pos = i2 >> 10;
        int co = cot * 16 + c16;
        unsigned wd = 0;
        #pragma unroll
        for (int jj = 0; jj < 4; jj++) {
            int ci = h * 32 + q1 * 16 + j * 4 + jj;
            int tv = tern_i(w2[(co * 64 + ci) * 9 + pos], d2v);
            wd |= ((unsigned)(tv & 255)) << (8 * jj);
        }
        ((int*)(ws + OFF_W2R))[i2] = (int)wd;
    } else {
        int i = idx - 18432;
        if (i < 64) {
            ((int*)(ws + OFF_B11))[i] = tern_i(b11[i], d11);
        } else if (i < 128) {
            ((int*)(ws + OFF_B1))[i - 64] = tern_i(b1[i - 64], d1);
        } else if (i < 192) {
            ((int*)(ws + OFF_B2))[i - 128] = tern_i(b2[i - 128], d2v);
        } else if (i < 216) {
            int j = i - 192;                // 0..23 : mapw[g*3 + (v+1)]
            int g = j / 3, s = j % 3;
            float v = (float)(s - 1);
            unsigned wd = 0;
            #pragma unroll
            for (int jj = 0; jj < 4; jj++) {
                int c = g * 4 + jj;
                float inv = __fdiv_rn(gp[c], __fsqrt_rn(__fadd_rn(vp[c], 1e-5f)));
                float sh  = __fsub_rn(bp[c], __fmul_rn(mp[c], inv));
                float z   = __fadd_rn(__fmul_rn(v, inv), sh);
                z = (z > 0.f) ? z : __fmul_rn(0.01f, z);
                wd |= ((unsigned)(tern_i(z, d1) & 255)) << (8 * jj);
            }
            ((int*)(ws + OFF_MAPW))[j] = (int)wd;
        } else if (i < 280) {
            int c = i - 216;
            float inv = __fdiv_rn(g1[c], __fsqrt_rn(__fadd_rn(v1[c], 1e-5f)));
            ((float*)(ws + OFF_S1))[c]  = inv;
            ((float*)(ws + OFF_SH1))[c] = __fsub_rn(be1[c], __fmul_rn(me1[c], inv));
        }
    }
}

// ---------------- K2: x -> raw tern [n][pix][32B] + mapped [n][pix][32B] ----------------
__global__ __launch_bounds__(256) void k_tern_x(const float* __restrict__ x,
                                                char* __restrict__ ws) {
    float d11 = __fmul_rn(0.1f, __uint_as_float(((const unsigned*)(ws + OFF_D))[0]));
    const int* mapw = (const int*)(ws + OFF_MAPW);
    int idx = blockIdx.x * 256 + threadIdx.x;      // 1,048,576 threads
    int pix = idx & 65535, n = idx >> 16;
    int gx = pix & 255;
    const float* xp = x + ((size_t)n * CIN << 16) + pix;
    int rw[8], mw[8];
    #pragma unroll
    for (int g = 0; g < 8; ++g) {
        unsigned r = 0, m = 0;
        #pragma unroll
        for (int j = 0; j < 4; ++j) {
            float v = xp[(size_t)(g * 4 + j) << 16];
            int tv = tern_i(v, d11);
            r |= ((unsigned)(tv & 255)) << (8 * j);
            m |= (((unsigned)mapw[g * 3 + tv + 1] >> (8 * j)) & 255u) << (8 * j);
        }
        rw[g] = (int)r; mw[g] = (int)m;
    }
    int4* o1 = (int4*)(ws + OFF_XTP) + ((size_t)idx * 2);
    o1[0] = make_int4(rw[0], rw[1], rw[2], rw[3]);
    o1[1] = make_int4(rw[4], rw[5], rw[6], rw[7]);
    int f = (gx & 1) ^ ((gx >> 2) & 1);            // half-swizzle for conv1 LDS reads
    int4* o2 = (int4*)(ws + OFF_XMAP) + ((size_t)idx * 2);
    o2[f]     = make_int4(mw[0], mw[1], mw[2], mw[3]);
    o2[f ^ 1] = make_int4(mw[4], mw[5], mw[6], mw[7]);
}

// ---------------- K3: fused conv1+conv2+conv11 per 8x8 output tile ----------------
// grid 11x11x16. 4 waves; lane = (q, c16); wave wv owns output pg2 = wv (16 px).
#define T2S 12   // t2L row stride in words (48B: 16B-aligned v4i reads, 2-way banks)
__global__ __launch_bounds__(256) void k_net(const char* __restrict__ ws,
                                             float* __restrict__ out) {
    __shared__ int mapL[676 * 8];   // [26x26 px][8 words] mapped x, halves pre-swizzled
    __shared__ int t2L[576 * T2S];  // [24x24 px][8 words + pad] conv1 out (co-half)
    int tid = threadIdx.x, bid = blockIdx.x;
    int tx = bid % 11; int tt = bid / 11; int ty = tt % 11; int n = tt / 11;
    int OH0 = ty * 8, OW0 = tx * 8;
    int Y0 = OH0 * 3 - 2, X0 = OW0 * 3 - 2;       // map region origin (26x26)
    int c16 = tid & 15, q = (tid >> 4) & 3, wv = tid >> 6;
    int q1 = q & 1, qh = q >> 1;
    const int* xmapn = (const int*)(ws + OFF_XMAP + ((size_t)n << 21));
    const int* xtpn  = (const int*)(ws + OFF_XTP  + ((size_t)n << 21));

    // ---- stage mapL (zeros OOB) ----
    for (int i = tid; i < 1352; i += 256) {
        int pix = i >> 1, hf = i & 1;
        int my = pix / 26, mx = pix - my * 26;
        int gy = Y0 + my, gxv = X0 + mx;
        int4 v = make_int4(0, 0, 0, 0);
        if ((unsigned)gy < H && (unsigned)gxv < W)
            v = *(const int4*)&xmapn[(gy * 256 + gxv) * 8 + hf * 4];
        *(int4*)&mapL[pix * 8 + hf * 4] = v;
    }

    // ---- conv11 from global (overlaps staging) ----
    int o = wv * 16 + c16;
    int oh8 = o >> 3, ow8 = o & 7;
    int gOH = OH0 + oh8, gOW = OW0 + ow8;
    bool pvalid = (gOH < OH) && (gOW < OW);
    const int* w11r = (const int*)(ws + OFF_W11R);
    v4i acc11[4];
    {
        v4i a[5];
        #pragma unroll
        for (int c = 0; c < 5; ++c) {
            int pos = 2 * c + qh;
            v4i z = {0, 0, 0, 0};
            if (pos < 9) {
                int kh = pos / 3, kw = pos - kh * 3;
                int ih = gOH * 3 - 1 + kh, iw = gOW * 3 - 1 + kw;
                if (pvalid && (unsigned)ih < H && (unsigned)iw < W)
                    z = *(const v4i*)&xtpn[(ih * 256 + iw) * 8 + q1 * 4];
            }
            a[c] = z;
        }
        #pragma unroll
        for (int cot = 0; cot < 4; ++cot) {
            v4i acc = {0, 0, 0, 0};
            #pragma unroll
            for (int c = 0; c < 5; ++c) {
                int pos = 2 * c + qh;
                v4i b = {0, 0, 0, 0};
                if (pos < 9)
                    b = *(const v4i*)&w11r[((pos * 2 + q1) * 4 + cot) * 64 + c16 * 4];
                acc = __builtin_amdgcn_mfma_i32_16x16x64_i8(a[c], b, acc, 0, 0, 0);
            }
            acc11[cot] = acc;
        }
    }
    __syncthreads();

    const int* w1r = (const int*)(ws + OFF_W1R);
    const int* w2r = (const int*)(ws + OFF_W2R);
    const int* b1i = (const int*)(ws + OFF_B1);
    const float* s1 = (const float*)(ws + OFF_S1);
    const float* sh1 = (const float*)(ws + OFF_SH1);
    float d2v = __fmul_rn(0.1f, __uint_as_float(((const unsigned*)(ws + OFF_D))[2]));
    v4i acc2[4];
    #pragma unroll
    for (int cot = 0; cot < 4; ++cot) { v4i z = {0,0,0,0}; acc2[cot] = z; }

    #pragma unroll 1
    for (int h = 0; h < 2; ++h) {
        // hoisted conv1 B-frags + epilogue consts for this co-half
        v4i bw1[5][2];
        int b1c[2]; float s1c[2], sh1c[2];
        #pragma unroll
        for (int cot = 0; cot < 2; ++cot) {
            int co = h * 32 + cot * 16 + c16;
            b1c[cot] = b1i[co]; s1c[cot] = s1[co]; sh1c[cot] = sh1[co];
        }
        #pragma unroll
        for (int c = 0; c < 5; ++c) {
            int pos = 2 * c + qh;
            #pragma unroll
            for (int cot = 0; cot < 2; ++cot) {
                v4i z = {0, 0, 0, 0};
                if (pos < 9)
                    z = *(const v4i*)&w1r[(((pos * 2 + q1) * 2 + h) * 2 + cot) * 64 + c16 * 4];
                bw1[c][cot] = z;
            }
        }
        // conv1: 9 pixel-groups per wave -> t2L
        #pragma unroll 1
        for (int pg = 0; pg < 9; ++pg) {
            int pbase = (wv * 9 + pg) * 16;
            int fp = pbase + c16;                 // 0..575
            int iy = fp / 24, ix = fp - iy * 24;
            v4i a[5];
            #pragma unroll
            for (int c = 0; c < 5; ++c) {
                int pos = 2 * c + qh;
                v4i z = {0, 0, 0, 0};
                if (pos < 9) {
                    int kh = pos / 3, kw = pos - kh * 3;
                    int my = iy + kh, mx = ix + kw;
                    int gxl = X0 + mx;
                    int hb = q1 ^ ((gxl & 1) ^ ((gxl >> 2) & 1));
                    z = *(const v4i*)&mapL[(my * 26 + mx) * 8 + hb * 4];
                }
                a[c] = z;
            }
            // write-pixel validity: t2 pixel p = pbase + q*4 + (c16&3); zero if its
            // global (y,x) is outside the 256x256 image (conv2 zero-padding).
            int pwr = pbase + q * 4 + (c16 & 3);
            int wy = pwr / 24, wx = pwr - wy * 24;
            bool wok = ((unsigned)(Y0 + 1 + wy) < H) && ((unsigned)(X0 + 1 + wx) < W);
            #pragma unroll
            for (int cot = 0; cot < 2; ++cot) {
                v4i acc = {0, 0, 0, 0};
                #pragma unroll
                for (int c = 0; c < 5; ++c)
                    acc = __builtin_amdgcn_mfma_i32_16x16x64_i8(a[c], bw1[c][cot], acc, 0, 0, 0);
                // epilogue: +b1, bn1, lrelu, tern(d2) -> byte per pixel (column of 4)
                unsigned wcol = 0;
                #pragma unroll
                for (int i = 0; i < 4; ++i) {
                    int vi = acc[i] + b1c[cot];
                    float z = __fadd_rn(__fmul_rn((float)vi, s1c[cot]), sh1c[cot]);
                    z = (z > 0.f) ? z : __fmul_rn(0.01f, z);
                    int tv = (fabsf(z) < d2v) ? 0 : (z > 0.f ? 1 : -1);
                    wcol |= ((unsigned)(tv & 255)) << (8 * i);
                }
                // 4x4 byte transpose across lanes (c16&3): cols(co) -> rows(pixel)
                unsigned y1 = (unsigned)__shfl_xor((int)wcol, 1);
                unsigned z1 = ((c16 & 1) == 0)
                            ? __builtin_amdgcn_perm(y1, wcol, 0x06020400u)
                            : __builtin_amdgcn_perm(y1, wcol, 0x03070105u);
                unsigned y2 = (unsigned)__shfl_xor((int)z1, 2);
                unsigned r  = ((c16 & 2) == 0)
                            ? __builtin_amdgcn_perm(y2, z1, 0x05040100u)
                            : __builtin_amdgcn_perm(y2, z1, 0x03020706u);
                t2L[pwr * T2S + cot * 4 + (c16 >> 2)] = wok ? (int)r : 0;
            }
        }
        __syncthreads();
        // conv2 partial (this ci-half) for wave's 16 output pixels
        {
            v4i a2[5];
            #pragma unroll
            for (int c = 0; c < 5; ++c) {
                int pos = 2 * c + qh;
                v4i z = {0, 0, 0, 0};
                if (pos < 9) {
                    int kh = pos / 3, kw = pos - kh * 3;
                    int p2 = (oh8 * 3 + kh) * 24 + (ow8 * 3 + kw);
                    z = *(const v4i*)&t2L[p2 * T2S + q1 * 4];
                }
                a2[c] = z;
            }
            #pragma unroll
            for (int cot = 0; cot < 4; ++cot) {
                v4i acc = acc2[cot];
                #pragma unroll
                for (int c = 0; c < 5; ++c) {
                    int pos = 2 * c + qh;
                    v4i b = {0, 0, 0, 0};
                    if (pos < 9)
                        b = *(const v4i*)&w2r[((((pos * 2 + h) * 2 + q1) * 4 + cot)) * 64 + c16 * 4];
                    acc = __builtin_amdgcn_mfma_i32_16x16x64_i8(a2[c], b, acc, 0, 0, 0);
                }
                acc2[cot] = acc;
            }
        }
        __syncthreads();   // before next half overwrites t2L
    }

    // ---- final epilogue: + b2 + conv11(+b11), lrelu -> out ----
    const int* b2i = (const int*)(ws + OFF_B2);
    const int* b11i = (const int*)(ws + OFF_B11);
    int pt0 = wv * 16 + q * 4;
    int ohh = OH0 + (pt0 >> 3);
    int oww = OW0 + (pt0 & 7);
    if (ohh < OH) {
        #pragma unroll
        for (int cot = 0; cot < 4; ++cot) {
            int co = cot * 16 + c16;
            int bc = b2i[co] + b11i[co];
            float f[4];
            #pragma unroll
            for (int i = 0; i < 4; ++i) {
                float z = (float)(acc2[cot][i] + acc11[cot][i] + bc);
                f[i] = (z > 0.f) ? z : __fmul_rn(0.01f, z);
            }
            float* op = out + ((size_t)(n * 64 + co)) * PIX + ohh * OW + oww;
            if (oww + 3 < OW) {
                *(float4*)op = make_float4(f[0], f[1], f[2], f[3]);
            } else {
                #pragma unroll
                for (int i = 0; i < 4; ++i)
                    if (oww + i < OW) op[i] = f[i];
            }
        }
    }
}

extern "C" void kernel_launch(void* const* d_in, const int* in_sizes, int n_in,
                              void* d_out, int out_size, void* d_ws, size_t ws_size,
                              hipStream_t stream) {
    const float* x    = (const float*)d_in[0];
    const float* w11  = (const float*)d_in[1];
    const float* b11  = (const float*)d_in[2];
    const float* w1   = (const float*)d_in[3];
    const float* b1   = (const float*)d_in[4];
    const float* w2   = (const float*)d_in[5];
    const float* b2   = (const float*)d_in[6];
    const float* gp   = (const float*)d_in[7];
    const float* bp   = (const float*)d_in[8];
    const float* mp   = (const float*)d_in[9];
    const float* vp   = (const float*)d_in[10];
    const float* g1   = (const float*)d_in[11];
    const float* be1  = (const float*)d_in[12];
    const float* me1  = (const float*)d_in[13];
    const float* v1   = (const float*)d_in[14];
    char* ws = (char*)d_ws;
    float* out = (float*)d_out;

    k_zero<<<1, 64, 0, stream>>>((unsigned*)(ws + OFF_D));
    k_absmax<<<48, 256, 0, stream>>>(w11, w1, w2, (unsigned*)(ws + OFF_D));
    k_prep<<<74, 256, 0, stream>>>(w11, w1, w2, b11, b1, b2,
                                   gp, bp, mp, vp, g1, be1, me1, v1, ws);
    k_tern_x<<<4096, 256, 0, stream>>>(x, ws);
    k_net<<<11 * 11 * B, 256, 0, stream>>>(ws, out);
}

// Round 9
// 144.044 us; speedup vs baseline: 49.2895x; 1.0390x over previous
//
#include <hip/hip_runtime.h>
#include <stdint.h>

#define B 16
#define CIN 32
#define C 64
#define H 256
#define W 256
#define OH 86
#define OW 86
#define PIX (OH*OW)   // 7396
#define PADW 272
#define PWORDS (PADW*PADW*8)   // 591,872 words per n-slice

typedef int v4i __attribute__((ext_vector_type(4)));

// ---- workspace layout (bytes) ----
#define OFF_D      0          // 3 u32: bit patterns of max|w11|, max|w1|, max|w2|
#define OFF_MAPW   64         // 24 i32: [g8][s3] packed mapped words (s = v+1)
#define OFF_B11    768        // 64 i32
#define OFF_B2     1280       // 64 i32
#define OFF_TLO    1536       // 64 i32: conv1 integer threshold lo (bias folded)
#define OFF_THI    1792       // 64 i32: conv1 integer threshold hi
#define OFF_W11R   4096       // 4608 i32: [pos9][q1 2][cot4][c16][j4]
#define OFF_W1R    24576      // 4608 i32: [pos9][q1 2][cot4][c16][j4]
#define OFF_W2R    45056      // 9216 i32: [pos9][cot4][c16][q4][j4]
#define OFF_XTP    262144     // padded [n16][272][272][32B] raw tern(x)  = 37.9MB
#define OFF_XMAP   38141952   // padded [n16][272][272][32B] mapped       = 37.9MB

__device__ __forceinline__ int tern_i(float t, float d) {
    return (fabsf(t) < d) ? 0 : (t > 0.f ? 1 : -1);
}

// ---------------- K0a: zero absmax slots + padded-tensor borders ----------------
__global__ __launch_bounds__(256) void k_pad(char* ws) {
    int idx = blockIdx.x * 256 + threadIdx.x;
    if (blockIdx.x == 0 && threadIdx.x < 3)
        ((unsigned*)(ws + OFF_D))[threadIdx.x] = 0u;
    if (idx >= 135168) return;                 // 16n x 8448 border cells
    int n = idx / 8448, c = idx - n * 8448;
    int row, col;
    if (c < 4352) {                            // rows {0,1,258..271} full width
        int r = c / 272; col = c - r * 272; row = (r < 2) ? r : r + 256;
    } else {                                   // rows 2..257, cols {0,1,258..271}
        int c2 = c - 4352; int k = c2 & 15;
        row = 2 + (c2 >> 4); col = (k < 2) ? k : k + 256;
    }
    size_t base = ((size_t)n * (PADW * PADW) + (size_t)row * PADW + col) * 2;  // int4 units
    int4 z = make_int4(0, 0, 0, 0);
    ((int4*)(ws + OFF_XTP))[base] = z;  ((int4*)(ws + OFF_XTP))[base + 1] = z;
    ((int4*)(ws + OFF_XMAP))[base] = z; ((int4*)(ws + OFF_XMAP))[base + 1] = z;
}

// ---------------- K0b: max|w| via bitwise atomicMax ----------------
__global__ __launch_bounds__(256) void k_absmax(const float* w11, const float* w1,
                                                const float* w2, unsigned* dws) {
    __shared__ unsigned red[256];
    int b = blockIdx.x >> 4, sub = blockIdx.x & 15;
    const float* p = (b == 0) ? w11 : (b == 1) ? w1 : w2;
    int n = (b == 2) ? 36864 : 18432;
    int chunk = (n + 15) >> 4;
    int lo = sub * chunk, hi = min(lo + chunk, n);
    unsigned m = 0;
    for (int i = lo + threadIdx.x; i < hi; i += 256)
        m = max(m, __float_as_uint(fabsf(p[i])));
    red[threadIdx.x] = m; __syncthreads();
    for (int s = 128; s > 0; s >>= 1) {
        if (threadIdx.x < s) red[threadIdx.x] = max(red[threadIdx.x], red[threadIdx.x + s]);
        __syncthreads();
    }
    if (threadIdx.x == 0) atomicMax(&dws[b], red[0]);
}

// ---------------- K1: pack weights, tables, integer thresholds ----------------
__global__ __launch_bounds__(256) void k_prep(const float* w11, const float* w1, const float* w2,
                                              const float* b11, const float* b1, const float* b2,
                                              const float* gp, const float* bp, const float* mp, const float* vp,
                                              const float* g1, const float* be1, const float* me1, const float* v1,
                                              char* ws) {
    const unsigned* dw = (const unsigned*)(ws + OFF_D);
    float d11 = __fmul_rn(0.1f, __uint_as_float(dw[0]));
    float d1  = __fmul_rn(0.1f, __uint_as_float(dw[1]));
    float d2v = __fmul_rn(0.1f, __uint_as_float(dw[2]));
    int idx = blockIdx.x * 256 + threadIdx.x;
    if (idx < 4608) {                       // w1r [pos][q1][cot4][c16][j]
        int j = idx & 3, c16 = (idx >> 2) & 15, cot = (idx >> 6) & 3;
        int q1 = (idx >> 8) & 1, pos = idx >> 9;
        int co = cot * 16 + c16;
        unsigned wd = 0;
        #pragma unroll
        for (int jj = 0; jj < 4; jj++) {
            int ci = q1 * 16 + j * 4 + jj;
            int tv = tern_i(w1[(co * 32 + ci) * 9 + pos], d1);
            wd |= ((unsigned)(tv & 255)) << (8 * jj);
        }
        ((int*)(ws + OFF_W1R))[idx] = (int)wd;
    } else if (idx < 9216) {                // w11r [pos][q1][cot4][c16][j]
        int i2 = idx - 4608;
        int j = i2 & 3, c16 = (i2 >> 2) & 15, cot = (i2 >> 6) & 3;
        int q1 = (i2 >> 8) & 1, pos = i2 >> 9;
        int co = cot * 16 + c16;
        unsigned wd = 0;
        #pragma unroll
        for (int jj = 0; jj < 4; jj++) {
            int ci = q1 * 16 + j * 4 + jj;
            int tv = tern_i(w11[(co * 32 + ci) * 9 + pos], d11);
            wd |= ((unsigned)(tv & 255)) << (8 * jj);
        }
        ((int*)(ws + OFF_W11R))[i2] = (int)wd;
    } else if (idx < 18432) {               // w2r [pos][cot4][c16][q4][j4]
        int i2 = idx - 9216;
        int j = i2 & 3, q = (i2 >> 2) & 3, c16 = (i2 >> 4) & 15;
        int cot = (i2 >> 8) & 3, pos = i2 >> 10;
        int co = cot * 16 + c16;
        unsigned wd = 0;
        #pragma unroll
        for (int jj = 0; jj < 4; jj++) {
            int ci = q * 16 + j * 4 + jj;
            int tv = tern_i(w2[(co * 64 + ci) * 9 + pos], d2v);
            wd |= ((unsigned)(tv & 255)) << (8 * jj);
        }
        ((int*)(ws + OFF_W2R))[i2] = (int)wd;
    } else {
        int i = idx - 18432;
        if (i < 64) {
            ((int*)(ws + OFF_B11))[i] = tern_i(b11[i], d11);
        } else if (i < 128) {
            ((int*)(ws + OFF_B2))[i - 64] = tern_i(b2[i - 64], d2v);
        } else if (i < 152) {
            int j = i - 128;                // 0..23 : mapw[g*3 + (v+1)]
            int g = j / 3, s = j % 3;
            float v = (float)(s - 1);
            unsigned wd = 0;
            #pragma unroll
            for (int jj = 0; jj < 4; jj++) {
                int c = g * 4 + jj;
                float inv = __fdiv_rn(gp[c], __fsqrt_rn(__fadd_rn(vp[c], 1e-5f)));
                float sh  = __fsub_rn(bp[c], __fmul_rn(mp[c], inv));
                float z   = __fadd_rn(__fmul_rn(v, inv), sh);
                z = (z > 0.f) ? z : __fmul_rn(0.01f, z);
                wd |= ((unsigned)(tern_i(z, d1) & 255)) << (8 * jj);
            }
            ((int*)(ws + OFF_MAPW))[j] = (int)wd;
        } else if (i < 216) {
            // integer thresholds for conv1 epilogue: class(vi) is monotone
            // nondecreasing in vi since inv = g1/sqrt(var+eps) >= 0.
            int co = i - 152;
            float inv = __fdiv_rn(g1[co], __fsqrt_rn(__fadd_rn(v1[co], 1e-5f)));
            float sh  = __fsub_rn(be1[co], __fmul_rn(me1[co], inv));
            int lo = 1000, hi = 1000;
            for (int vi = -290; vi <= 290; ++vi) {
                float z = __fadd_rn(__fmul_rn((float)vi, inv), sh);
                z = (z > 0.f) ? z : __fmul_rn(0.01f, z);
                int cls = (fabsf(z) < d2v) ? 0 : (z > 0.f ? 1 : -1);
                if (cls >= 0 && lo == 1000) lo = vi;
                if (cls == 1 && hi == 1000) hi = vi;
            }
            int b1t = tern_i(b1[co], d1);   // fold conv1 ternary bias
            ((int*)(ws + OFF_TLO))[co] = lo - b1t;
            ((int*)(ws + OFF_THI))[co] = hi - b1t;
        }
    }
}

// ---------------- K2: x -> padded raw tern + padded mapped ----------------
__global__ __launch_bounds__(256) void k_tern_x(const float* __restrict__ x,
                                                char* __restrict__ ws) {
    float d11 = __fmul_rn(0.1f, __uint_as_float(((const unsigned*)(ws + OFF_D))[0]));
    const int* mapw = (const int*)(ws + OFF_MAPW);
    int idx = blockIdx.x * 256 + threadIdx.x;      // 1,048,576 threads
    int pix = idx & 65535, n = idx >> 16;
    int y = pix >> 8, xq = pix & 255;
    const float* xp = x + ((size_t)n * CIN << 16) + pix;
    int rw[8], mw[8];
    #pragma unroll
    for (int g = 0; g < 8; ++g) {
        unsigned r = 0, m = 0;
        #pragma unroll
        for (int j = 0; j < 4; ++j) {
            float v = xp[(size_t)(g * 4 + j) << 16];
            int tv = tern_i(v, d11);
            r |= ((unsigned)(tv & 255)) << (8 * j);
            m |= (((unsigned)mapw[g * 3 + tv + 1] >> (8 * j)) & 255u) << (8 * j);
        }
        rw[g] = (int)r; mw[g] = (int)m;
    }
    size_t base = ((size_t)n * (PADW * PADW) + (size_t)(y + 2) * PADW + (xq + 2)) * 2;
    int4* o1 = (int4*)(ws + OFF_XTP) + base;
    o1[0] = make_int4(rw[0], rw[1], rw[2], rw[3]);
    o1[1] = make_int4(rw[4], rw[5], rw[6], rw[7]);
    int4* o2 = (int4*)(ws + OFF_XMAP) + base;
    o2[0] = make_int4(mw[0], mw[1], mw[2], mw[3]);
    o2[1] = make_int4(mw[4], mw[5], mw[6], mw[7]);
}

// ---------------- K3: fused conv1+conv2+conv11, one barrier ----------------
// grid 11x11x16. 4 waves; lane = (q,c16); q1 = ci-half, qh = pos parity.
__global__ __launch_bounds__(256, 3) void k_net(const char* __restrict__ ws,
                                                float* __restrict__ out) {
    __shared__ int t2L[576 * 20];   // [24x24 px][16 co-words + 4 pad] = 46080 B
    int tid = threadIdx.x, bid = blockIdx.x;
    int tx = bid % 11; int tt = bid / 11; int ty = tt % 11; int n = tt / 11;
    int OH0 = ty * 8, OW0 = tx * 8;
    int Y0 = OH0 * 3 - 2, X0 = OW0 * 3 - 2;      // 26x26 halo origin (global)
    int c16 = tid & 15, q = (tid >> 4) & 3, wv = tid >> 6;
    int q1 = q & 1, qh = q >> 1;
    const int* xmapn = (const int*)(ws + OFF_XMAP) + (size_t)n * PWORDS;
    const int* xtpn  = (const int*)(ws + OFF_XTP)  + (size_t)n * PWORDS;

    // ---- conv1: B-frags for all 64 co hoisted (80 VGPR) ----
    const int* w1r = (const int*)(ws + OFF_W1R);
    v4i bw1[5][4];
    #pragma unroll
    for (int c = 0; c < 5; ++c) {
        int pos = 2 * c + qh;
        #pragma unroll
        for (int ct = 0; ct < 4; ++ct) {
            v4i z = {0, 0, 0, 0};
            if (pos < 9) z = *(const v4i*)&w1r[((pos * 2 + q1) * 4 + ct) * 64 + c16 * 4];
            bw1[c][ct] = z;
        }
    }
    const int* TLO = (const int*)(ws + OFF_TLO);
    const int* THI = (const int*)(ws + OFF_THI);
    int tlo[4], thi[4];
    #pragma unroll
    for (int ct = 0; ct < 4; ++ct) { tlo[ct] = TLO[ct * 16 + c16]; thi[ct] = THI[ct * 16 + c16]; }

    int Yb = Y0 + 2, Xb = X0 + 2;                // padded coords
    #pragma unroll 1
    for (int pg = 0; pg < 9; ++pg) {
        int pbase = (wv * 9 + pg) * 16;
        int fp = pbase + c16;                    // A-row pixel (0..575)
        int iy = fp / 24, ix = fp - iy * 24;
        v4i a[5];
        #pragma unroll
        for (int c = 0; c < 5; ++c) {
            int pos = 2 * c + qh;
            v4i z = {0, 0, 0, 0};
            if (pos < 9) {
                int kh = pos / 3, kw = pos - kh * 3;
                z = *(const v4i*)&xmapn[((Yb + iy + kh) * PADW + (Xb + ix + kw)) * 8 + q1 * 4];
            }
            a[c] = z;
        }
        int pwr = pbase + q * 4 + (c16 & 3);     // write pixel after transpose
        int wy = pwr / 24, wx = pwr - wy * 24;
        bool wok = ((unsigned)(Y0 + 1 + wy) < H) && ((unsigned)(X0 + 1 + wx) < W);
        #pragma unroll
        for (int ct = 0; ct < 4; ++ct) {
            v4i acc = {0, 0, 0, 0};
            #pragma unroll
            for (int c = 0; c < 5; ++c)
                acc = __builtin_amdgcn_mfma_i32_16x16x64_i8(a[c], bw1[c][ct], acc, 0, 0, 0);
            // integer-threshold epilogue: class = (vi>=lo)+(vi>=hi)-1
            unsigned wcol = 0;
            #pragma unroll
            for (int i = 0; i < 4; ++i) {
                int cls = (acc[i] >= tlo[ct] ? 1 : 0) + (acc[i] >= thi[ct] ? 1 : 0) - 1;
                wcol |= ((unsigned)(cls & 255)) << (8 * i);
            }
            // 4x4 byte transpose across lanes (c16&3): co-major -> pixel-major
            unsigned y1 = (unsigned)__shfl_xor((int)wcol, 1);
            unsigned z1 = ((c16 & 1) == 0)
                        ? __builtin_amdgcn_perm(y1, wcol, 0x06020400u)
                        : __builtin_amdgcn_perm(y1, wcol, 0x03070105u);
            unsigned y2 = (unsigned)__shfl_xor((int)z1, 2);
            unsigned r  = ((c16 & 2) == 0)
                        ? __builtin_amdgcn_perm(y2, z1, 0x05040100u)
                        : __builtin_amdgcn_perm(y2, z1, 0x03020706u);
            t2L[pwr * 20 + ct * 4 + (c16 >> 2)] = wok ? (int)r : 0;
        }
    }
    __syncthreads();

    // ---- conv11 A-loads (padded, unconditional) ----
    int o = wv * 16 + c16;
    int oh8 = o >> 3, ow8 = o & 7;
    int gOH = OH0 + oh8, gOW = OW0 + ow8;
    v4i a11[5];
    #pragma unroll
    for (int c = 0; c < 5; ++c) {
        int pos = 2 * c + qh;
        v4i z = {0, 0, 0, 0};
        if (pos < 9) {
            int kh = pos / 3, kw = pos - kh * 3;
            int ih = gOH * 3 - 1 + kh, iw = gOW * 3 - 1 + kw;
            z = *(const v4i*)&xtpn[((ih + 2) * PADW + (iw + 2)) * 8 + q1 * 4];
        }
        a11[c] = z;
    }
    // ---- conv2 A from LDS (K = all 64 ci per chunk) ----
    v4i a2[9];
    #pragma unroll
    for (int pos = 0; pos < 9; ++pos) {
        int kh = pos / 3, kw = pos - kh * 3;
        int p2 = (oh8 * 3 + kh) * 24 + ow8 * 3 + kw;
        a2[pos] = *(const v4i*)&t2L[p2 * 20 + q * 4];
    }
    const int* w2r = (const int*)(ws + OFF_W2R);
    const int* w11r = (const int*)(ws + OFF_W11R);
    v4i acc2[4], acc11[4];
    #pragma unroll
    for (int ct = 0; ct < 4; ++ct) {
        v4i acc = {0, 0, 0, 0};
        #pragma unroll
        for (int pos = 0; pos < 9; ++pos) {
            v4i b = *(const v4i*)&w2r[((pos * 4 + ct) * 16 + c16) * 16 + q * 4];
            acc = __builtin_amdgcn_mfma_i32_16x16x64_i8(a2[pos], b, acc, 0, 0, 0);
        }
        acc2[ct] = acc;
        v4i acc1 = {0, 0, 0, 0};
        #pragma unroll
        for (int c = 0; c < 5; ++c) {
            int pos = 2 * c + qh;
            v4i b = {0, 0, 0, 0};
            if (pos < 9) b = *(const v4i*)&w11r[((pos * 2 + q1) * 4 + ct) * 64 + c16 * 4];
            acc1 = __builtin_amdgcn_mfma_i32_16x16x64_i8(a11[c], b, acc1, 0, 0, 0);
        }
        acc11[ct] = acc1;
    }

    // ---- final epilogue: + b2 + b11, lrelu -> out ----
    const int* b2i = (const int*)(ws + OFF_B2);
    const int* b11i = (const int*)(ws + OFF_B11);
    int pt0 = wv * 16 + q * 4;
    int ohh = OH0 + (pt0 >> 3);
    int oww = OW0 + (pt0 & 7);
    if (ohh < OH) {
        #pragma unroll
        for (int ct = 0; ct < 4; ++ct) {
            int co = ct * 16 + c16;
            int bc = b2i[co] + b11i[co];
            float f[4];
            #pragma unroll
            for (int i = 0; i < 4; ++i) {
                float z = (float)(acc2[ct][i] + acc11[ct][i] + bc);
                f[i] = (z > 0.f) ? z : __fmul_rn(0.01f, z);
            }
            float* op = out + ((size_t)(n * 64 + co)) * PIX + ohh * OW + oww;
            if (oww + 3 < OW) {
                *(float4*)op = make_float4(f[0], f[1], f[2], f[3]);
            } else {
                #pragma unroll
                for (int i = 0; i < 4; ++i)
                    if (oww + i < OW) op[i] = f[i];
            }
        }
    }
}

extern "C" void kernel_launch(void* const* d_in, const int* in_sizes, int n_in,
                              void* d_out, int out_size, void* d_ws, size_t ws_size,
                              hipStream_t stream) {
    const float* x    = (const float*)d_in[0];
    const float* w11  = (const float*)d_in[1];
    const float* b11  = (const float*)d_in[2];
    const float* w1   = (const float*)d_in[3];
    const float* b1   = (const float*)d_in[4];
    const float* w2   = (const float*)d_in[5];
    const float* b2   = (const float*)d_in[6];
    const float* gp   = (const float*)d_in[7];
    const float* bp   = (const float*)d_in[8];
    const float* mp   = (const float*)d_in[9];
    const float* vp   = (const float*)d_in[10];
    const float* g1   = (const float*)d_in[11];
    const float* be1  = (const float*)d_in[12];
    const float* me1  = (const float*)d_in[13];
    const float* v1   = (const float*)d_in[14];
    char* ws = (char*)d_ws;
    float* out = (float*)d_out;

    k_pad<<<528, 256, 0, stream>>>(ws);
    k_absmax<<<48, 256, 0, stream>>>(w11, w1, w2, (unsigned*)(ws + OFF_D));
    k_prep<<<73, 256, 0, stream>>>(w11, w1, w2, b11, b1, b2,
                                   gp, bp, mp, vp, g1, be1, me1, v1, ws);
    k_tern_x<<<4096, 256, 0, stream>>>(x, ws);
    k_net<<<11 * 11 * B, 256, 0, stream>>>(ws, out);
}